// Round 1
// baseline (761.872 us; speedup 1.0000x reference)
//
#include <hip/hip_runtime.h>
#include <math.h>

#define Bb 16
#define Tt 64
#define Nn 64
#define Ss 4
#define Dd 128
#define Hh 8
#define HD 16
#define BN 1024
#define G3 384   // 3*D

// workspace layout (in floats)
#define OFF_WX   0                              // 4*384
#define OFF_BX   1536                           // 384
#define OFF_U1   1920                           // 128*8
#define OFF_U2   2944                           // 128*8
#define OFF_YS   4096                           // T*BN*D
#define OFF_KK   (OFF_YS + Tt*BN*Dd)            // B*H*T*N*HD
#define OFF_QQ   (OFF_KK + Bb*Hh*Tt*Nn*HD)
#define OFF_VW1  (OFF_QQ + Bb*Hh*Tt*Nn*HD)      // B*H*T*N
#define OFF_VW2  (OFF_VW1 + Bb*Hh*Tt*Nn)
#define OFF_E    (OFF_VW2 + Bb*Hh*Tt*Nn)        // B*N*N
#define OFF_VV   (OFF_E + Bb*Nn*Nn)             // BN*D
#define WS_FLOATS (OFF_VV + BN*Dd)

// ---------------- kernel 0: fold weights ----------------
__global__ __launch_bounds__(384) void k_precompute(
    const float* __restrict__ W_se, const float* __restrict__ b_se,
    const float* __restrict__ W_ih, const float* __restrict__ b_ih,
    const float* __restrict__ W_vc, const float* __restrict__ W_att,
    float* __restrict__ ws) {
  const int c = threadIdx.x; // 0..383
  float* Wx = ws + OFF_WX; float* bx = ws + OFF_BX;
  float* u1 = ws + OFF_U1; float* u2 = ws + OFF_U2;
  // W_x[s][c] = sum_k W_se[s][k]*W_ih[k][c];  b_x[c] = b_ih[c] + sum_k b_se[k]*W_ih[k][c]
  float accb = b_ih[c];
  float a0 = 0.f, a1 = 0.f, a2 = 0.f, a3 = 0.f;
  for (int k = 0; k < Dd; ++k) {
    float w = W_ih[k*G3 + c];
    accb = fmaf(b_se[k], w, accb);
    a0 = fmaf(W_se[0*Dd + k], w, a0);
    a1 = fmaf(W_se[1*Dd + k], w, a1);
    a2 = fmaf(W_se[2*Dd + k], w, a2);
    a3 = fmaf(W_se[3*Dd + k], w, a3);
  }
  bx[c] = accb;
  Wx[0*G3 + c] = a0; Wx[1*G3 + c] = a1; Wx[2*G3 + c] = a2; Wx[3*G3 + c] = a3;
  // u1[k][h] = sum_d W_vc[k][h*16+d]*W_att[h*16+d]; u2 uses W_att[128+...]
  for (int idx = c; idx < Dd*Hh; idx += 384) {
    int k = idx >> 3, h = idx & 7;
    float s1 = 0.f, s2 = 0.f;
    for (int d = 0; d < HD; ++d) {
      float v = W_vc[k*Dd + h*HD + d];
      s1 = fmaf(v, W_att[h*HD + d], s1);
      s2 = fmaf(v, W_att[Dd + h*HD + d], s2);
    }
    u1[k*Hh + h] = s1;
    u2[k*Hh + h] = s2;
  }
}

// ---------------- kernel 1: GRU over T steps (row-local recurrence) ----------------
__global__ __launch_bounds__(384) void k_gru(
    const float* __restrict__ x, const float* __restrict__ W_init,
    const float* __restrict__ b_init, const float* __restrict__ W_hh,
    const float* __restrict__ b_hh, float* __restrict__ ws) {
  __shared__ float h_lds[4][Dd];
  __shared__ float g_lds[4][4*Dd];   // [r|z|in|hn] per row
  __shared__ float xt[4][Ss];
  __shared__ float Wx_l[4][G3];
  __shared__ float bx_l[G3];
  const int tid = threadIdx.x;
  const int blk = blockIdx.x;
  const int row0 = blk * 4;
  const int b = row0 >> 6;
  const int n0 = row0 & 63;
  float* ys = ws + OFF_YS;
  const float* Wx = ws + OFF_WX;
  const float* bxp = ws + OFF_BX;

  // stage folded input weights
  bx_l[tid] = bxp[tid];
  #pragma unroll
  for (int s = 0; s < 4; ++s) Wx_l[s][tid] = Wx[s*G3 + tid];
  // h0 = x[:,0] @ W_init + b_init
  if (tid < Dd) {
    for (int r = 0; r < 4; ++r) {
      const float* xr = x + ((size_t)(b*(Tt+1) + 0)*Nn + (n0 + r))*Ss;
      float acc = b_init[tid];
      #pragma unroll
      for (int s = 0; s < Ss; ++s) acc = fmaf(xr[s], W_init[s*Dd + tid], acc);
      h_lds[r][tid] = acc;
    }
  }
  // stage x frame 0
  if (tid >= 320 && tid < 336) {
    int q = tid - 320; int r = q >> 2, s = q & 3;
    xt[r][s] = x[((size_t)(b*(Tt+1) + 0)*Nn + (n0 + r))*Ss + s];
  }
  const int c = tid;
  const float bhh = b_hh[c];
  __syncthreads();
  const float wx0 = Wx_l[0][c], wx1 = Wx_l[1][c], wx2 = Wx_l[2][c], wx3 = Wx_l[3][c];
  const float bxv = bx_l[c];

  for (int t = 0; t < Tt; ++t) {
    // gh[r][c] = h[r] . W_hh[:,c] + b_hh[c]
    float acc[4] = {bhh, bhh, bhh, bhh};
    for (int k = 0; k < Dd; k += 4) {
      float w0 = W_hh[(k+0)*G3 + c];
      float w1 = W_hh[(k+1)*G3 + c];
      float w2 = W_hh[(k+2)*G3 + c];
      float w3 = W_hh[(k+3)*G3 + c];
      #pragma unroll
      for (int r = 0; r < 4; ++r) {
        float4 hv = *(const float4*)&h_lds[r][k];
        acc[r] = fmaf(hv.x, w0, acc[r]);
        acc[r] = fmaf(hv.y, w1, acc[r]);
        acc[r] = fmaf(hv.z, w2, acc[r]);
        acc[r] = fmaf(hv.w, w3, acc[r]);
      }
    }
    float gi[4];
    #pragma unroll
    for (int r = 0; r < 4; ++r) {
      float g = bxv;
      g = fmaf(xt[r][0], wx0, g);
      g = fmaf(xt[r][1], wx1, g);
      g = fmaf(xt[r][2], wx2, g);
      g = fmaf(xt[r][3], wx3, g);
      gi[r] = g;
    }
    if (c < 2*Dd) {
      #pragma unroll
      for (int r = 0; r < 4; ++r) g_lds[r][c] = acc[r] + gi[r];
    } else {
      #pragma unroll
      for (int r = 0; r < 4; ++r) { g_lds[r][c] = gi[r]; g_lds[r][c + Dd] = acc[r]; }
    }
    __syncthreads();
    if (tid < Dd) {
      const int d = tid;
      #pragma unroll
      for (int r = 0; r < 4; ++r) {
        float rg = 1.f/(1.f + expf(-g_lds[r][d]));
        float zg = 1.f/(1.f + expf(-g_lds[r][Dd + d]));
        float ng = tanhf(fmaf(rg, g_lds[r][3*Dd + d], g_lds[r][2*Dd + d]));
        float hn = fmaf(zg, h_lds[r][d] - ng, ng);   // (1-z)*n + z*h
        h_lds[r][d] = hn;
        ys[(size_t)(t*BN + row0 + r)*Dd + d] = hn;
      }
    }
    // stage x frame t+1 (frame T exists; harmless extra stage on last iter)
    if (tid >= 320 && tid < 336) {
      int q = tid - 320; int r = q >> 2, s = q & 3;
      int tn = (t + 1 <= Tt) ? (t + 1) : Tt;
      xt[r][s] = x[((size_t)(b*(Tt+1) + tn)*Nn + (n0 + r))*Ss + s];
    }
    __syncthreads();
  }
}

// ---------------- kernel 2: k,q projections + vw scalars ----------------
__global__ __launch_bounds__(256) void k_kqv(
    const float* __restrict__ W_kc, const float* __restrict__ W_qc,
    float* __restrict__ ws) {
  __shared__ float ysl[64][Dd];  // 32KB
  const int tid = threadIdx.x;
  const int blk = blockIdx.x;    // b*T + t
  const int b = blk >> 6;
  const int t = blk & 63;
  const float* ysrc = ws + OFF_YS + (size_t)(t*BN + b*64)*Dd;
  for (int idx = tid; idx < 64*Dd; idx += 256) ((float*)ysl)[idx] = ysrc[idx];
  __syncthreads();

  const float* W = (tid < Dd) ? (W_kc + tid) : (W_qc + (tid - Dd));
  float acc[64];
  #pragma unroll
  for (int r = 0; r < 64; ++r) acc[r] = 0.f;
  for (int k = 0; k < Dd; k += 4) {
    float w0 = W[(k+0)*Dd];
    float w1 = W[(k+1)*Dd];
    float w2 = W[(k+2)*Dd];
    float w3 = W[(k+3)*Dd];
    #pragma unroll
    for (int r = 0; r < 64; ++r) {
      float4 hv = *(const float4*)&ysl[r][k];
      acc[r] = fmaf(hv.x, w0, acc[r]);
      acc[r] = fmaf(hv.y, w1, acc[r]);
      acc[r] = fmaf(hv.z, w2, acc[r]);
      acc[r] = fmaf(hv.w, w3, acc[r]);
    }
  }
  // write k or q in [b][h][t][i][d] layout
  float* dst = ws + ((tid < Dd) ? OFF_KK : OFF_QQ);
  const int cc = tid & 127;
  const int h = cc >> 4, d = cc & 15;
  const size_t base = ((size_t)(b*Hh + h)*Tt + t)*(Nn*HD) + d;
  #pragma unroll
  for (int r = 0; r < 64; ++r) dst[base + (size_t)r*HD] = acc[r];

  // vw1/vw2: [b][h][t][i]
  const float* u1 = ws + OFF_U1;
  const float* u2 = ws + OFF_U2;
  for (int idx = tid; idx < 64*HD; idx += 256) {
    int r = idx >> 4, g = idx & 15, h2 = g >> 1, which = g & 1;
    const float* u = which ? u2 : u1;
    float s = 0.f;
    for (int k = 0; k < Dd; ++k) s = fmaf(ysl[r][k], u[k*Hh + h2], s);
    float* vw = ws + (which ? OFF_VW2 : OFF_VW1);
    vw[((size_t)(b*Hh + h2)*Tt + t)*Nn + r] = s;
  }
}

// ---------------- kernel 3: per-pair temporal online softmax -> e partials ----------------
__global__ __launch_bounds__(256) void k_attn(float* __restrict__ ws) {
  __shared__ float k_l[16*HD];
  __shared__ float q_l[HD*65];  // transposed, padded
  __shared__ float vw1_l[16], vw2_l[16];
  const int tid = threadIdx.x;
  const int blk = blockIdx.x;         // (b*H+h)*4 + quarter
  const int quarter = blk & 3;
  const int bh = blk >> 2;
  const int b = bh >> 3;
  const int i0 = quarter * 16;
  const float* kk = ws + OFF_KK + (size_t)bh*Tt*Nn*HD;
  const float* qq = ws + OFF_QQ + (size_t)bh*Tt*Nn*HD;
  const float* vw1 = ws + OFF_VW1 + (size_t)bh*Tt*Nn;
  const float* vw2 = ws + OFF_VW2 + (size_t)bh*Tt*Nn;
  float* e = ws + OFF_E + (size_t)b*Nn*Nn;
  const int j = tid & 63, wq = tid >> 6;
  float m[4], Ssum[4], A1[4], A2[4];
  #pragma unroll
  for (int p = 0; p < 4; ++p) { m[p] = -1e30f; Ssum[p] = 0.f; A1[p] = 0.f; A2[p] = 0.f; }
  const float scale = 0.08838834764831845f; // 1/sqrt(128)

  for (int t = 0; t < Tt; ++t) {
    __syncthreads();
    k_l[tid] = kk[(size_t)t*Nn*HD + i0*HD + tid];
    for (int idx = tid; idx < Nn*HD; idx += 256) {
      int jj = idx >> 4, d = idx & 15;
      q_l[d*65 + jj] = qq[(size_t)t*Nn*HD + idx];
    }
    if (tid < 16) vw1_l[tid] = vw1[(size_t)t*Nn + i0 + tid];
    else if (tid < 32) vw2_l[tid - 16] = vw2[(size_t)t*Nn + i0 + tid - 16];
    __syncthreads();
    float qr[16];
    #pragma unroll
    for (int d = 0; d < 16; ++d) qr[d] = q_l[d*65 + j];
    #pragma unroll
    for (int p = 0; p < 4; ++p) {
      const int il = wq + 4*p;
      float s = 0.f;
      #pragma unroll
      for (int d = 0; d < 16; ++d) s = fmaf(qr[d], k_l[il*HD + d], s);
      s *= scale;
      float mn = fmaxf(m[p], s);
      float cc = __expf(m[p] - mn);
      float pp = __expf(s - mn);
      Ssum[p] = fmaf(Ssum[p], cc, pp);
      A1[p] = fmaf(A1[p], cc, pp * vw1_l[il]);
      A2[p] = fmaf(A2[p], cc, pp * vw2_l[il]);
      m[p] = mn;
    }
  }
  #pragma unroll
  for (int p = 0; p < 4; ++p) {
    const int i = i0 + wq + 4*p;
    float inv = 1.f / Ssum[p];
    atomicAdd(&e[i*Nn + j], A1[p] * inv);
    atomicAdd(&e[j*Nn + i], A2[p] * inv);
  }
}

// ---------------- kernel 4: decode GRU step + vv ----------------
__global__ __launch_bounds__(384) void k_decode(
    const float* __restrict__ x, const float* __restrict__ W_hh,
    const float* __restrict__ b_hh, const float* __restrict__ W_val,
    const float* __restrict__ b_val, float* __restrict__ ws) {
  __shared__ float h_lds[4][Dd];
  __shared__ float g_lds[4][4*Dd];
  __shared__ float xt[4][Ss];
  const int tid = threadIdx.x;
  const int blk = blockIdx.x;
  const int row0 = blk * 4;
  const int b = row0 >> 6;
  const int n0 = row0 & 63;
  const float* ys = ws + OFF_YS;
  const float* Wx = ws + OFF_WX;
  const float* bxp = ws + OFF_BX;
  if (tid < Dd) {
    for (int r = 0; r < 4; ++r)
      h_lds[r][tid] = ys[(size_t)((Tt-1)*BN + row0 + r)*Dd + tid];
  }
  if (tid >= 320 && tid < 336) {
    int q = tid - 320; int r = q >> 2, s = q & 3;
    xt[r][s] = x[((size_t)(b*(Tt+1) + Tt)*Nn + (n0 + r))*Ss + s];
  }
  const int c = tid;
  const float bhh = b_hh[c];
  const float wx0 = Wx[0*G3 + c], wx1 = Wx[1*G3 + c], wx2 = Wx[2*G3 + c], wx3 = Wx[3*G3 + c];
  const float bxv = bxp[c];
  __syncthreads();
  float acc[4] = {bhh, bhh, bhh, bhh};
  for (int k = 0; k < Dd; k += 4) {
    float w0 = W_hh[(k+0)*G3 + c];
    float w1 = W_hh[(k+1)*G3 + c];
    float w2 = W_hh[(k+2)*G3 + c];
    float w3 = W_hh[(k+3)*G3 + c];
    #pragma unroll
    for (int r = 0; r < 4; ++r) {
      float4 hv = *(const float4*)&h_lds[r][k];
      acc[r] = fmaf(hv.x, w0, acc[r]);
      acc[r] = fmaf(hv.y, w1, acc[r]);
      acc[r] = fmaf(hv.z, w2, acc[r]);
      acc[r] = fmaf(hv.w, w3, acc[r]);
    }
  }
  float gi[4];
  #pragma unroll
  for (int r = 0; r < 4; ++r) {
    float g = bxv;
    g = fmaf(xt[r][0], wx0, g);
    g = fmaf(xt[r][1], wx1, g);
    g = fmaf(xt[r][2], wx2, g);
    g = fmaf(xt[r][3], wx3, g);
    gi[r] = g;
  }
  if (c < 2*Dd) {
    #pragma unroll
    for (int r = 0; r < 4; ++r) g_lds[r][c] = acc[r] + gi[r];
  } else {
    #pragma unroll
    for (int r = 0; r < 4; ++r) { g_lds[r][c] = gi[r]; g_lds[r][c + Dd] = acc[r]; }
  }
  __syncthreads();
  if (tid < Dd) {
    const int d = tid;
    #pragma unroll
    for (int r = 0; r < 4; ++r) {
      float rg = 1.f/(1.f + expf(-g_lds[r][d]));
      float zg = 1.f/(1.f + expf(-g_lds[r][Dd + d]));
      float ng = tanhf(fmaf(rg, g_lds[r][3*Dd + d], g_lds[r][2*Dd + d]));
      float hn = fmaf(zg, h_lds[r][d] - ng, ng);
      h_lds[r][d] = hn;
    }
  }
  __syncthreads();
  // vv = h2 @ W_val + b_val
  if (tid < Dd) {
    const int c2 = tid;
    for (int r = 0; r < 4; ++r) {
      float a = b_val[c2];
      for (int k = 0; k < Dd; k += 4) {
        float4 hv = *(const float4*)&h_lds[r][k];
        a = fmaf(hv.x, W_val[(k+0)*Dd + c2], a);
        a = fmaf(hv.y, W_val[(k+1)*Dd + c2], a);
        a = fmaf(hv.z, W_val[(k+2)*Dd + c2], a);
        a = fmaf(hv.w, W_val[(k+3)*Dd + c2], a);
      }
      ws[OFF_VV + (size_t)(row0 + r)*Dd + c2] = a;
    }
  }
}

// ---------------- kernel 5: weight/p/dec/mu/sig ----------------
__global__ __launch_bounds__(256) void k_final(
    const float* __restrict__ W_dec, const float* __restrict__ b_dec,
    const float* __restrict__ W_mu, const float* __restrict__ b_mu,
    const float* __restrict__ W_sig, const float* __restrict__ b_sig,
    const float* __restrict__ b_att, float* __restrict__ ws,
    float* __restrict__ out) {
  __shared__ float vvl[64][Dd];  // 32KB
  __shared__ float wl[16][64];
  __shared__ float pl[16][Dd];
  __shared__ float ddl[16][Dd];
  const int tid = threadIdx.x;
  const int blk = blockIdx.x;
  const int b = blk >> 2, iq = blk & 3, i0 = iq*16;
  const float* vv = ws + OFF_VV + (size_t)b*64*Dd;
  const float* e = ws + OFF_E + (size_t)b*Nn*Nn;
  const float batt = b_att[0];
  for (int idx = tid; idx < 64*Dd; idx += 256) ((float*)vvl)[idx] = vv[idx];
  for (int idx = tid; idx < 16*64; idx += 256) {
    int il = idx >> 6, jj = idx & 63;
    int i = i0 + il;
    wl[il][jj] = (i == jj) ? 0.f : tanhf(e[i*Nn + jj] + batt + 0.5f);
  }
  __syncthreads();
  {
    const int d = tid & 127, ih = tid >> 7;
    #pragma unroll
    for (int kk2 = 0; kk2 < 8; ++kk2) {
      int il = ih*8 + kk2;
      float a = 0.f;
      for (int jj = 0; jj < 64; ++jj) a = fmaf(wl[il][jj], vvl[jj][d], a);
      pl[il][d] = a * (1.f/64.f);
    }
  }
  __syncthreads();
  {
    const int e2 = tid & 127, ih = tid >> 7;
    #pragma unroll
    for (int kk2 = 0; kk2 < 8; ++kk2) {
      int il = ih*8 + kk2;
      float a = b_dec[e2];
      for (int c2 = 0; c2 < Dd; ++c2) a = fmaf(vvl[i0 + il][c2], W_dec[c2*Dd + e2], a);
      for (int c2 = 0; c2 < Dd; ++c2) a = fmaf(pl[il][c2], W_dec[(Dd + c2)*Dd + e2], a);
      ddl[il][e2] = a;
    }
  }
  __syncthreads();
  if (tid < 128) {
    const int il = tid >> 3, g = tid & 7, which = g >> 2, s = g & 3;
    const float* W = which ? W_sig : W_mu;
    float a = which ? b_sig[s] : b_mu[s];
    for (int k = 0; k < Dd; ++k) a = fmaf(ddl[il][k], W[k*Ss + s], a);
    if (which) a = 1.f/(1.f + expf(-a)) + 1e-6f;
    out[(size_t)which*(Bb*Nn*Ss) + (size_t)(b*64 + i0 + il)*Ss + s] = a;
  }
}

extern "C" void kernel_launch(void* const* d_in, const int* in_sizes, int n_in,
                              void* d_out, int out_size, void* d_ws, size_t ws_size,
                              hipStream_t stream) {
  const float* x     = (const float*)d_in[0];
  const float* W_se  = (const float*)d_in[1];
  const float* b_se  = (const float*)d_in[2];
  const float* W_init= (const float*)d_in[3];
  const float* b_init= (const float*)d_in[4];
  const float* W_ih  = (const float*)d_in[5];
  const float* W_hh  = (const float*)d_in[6];
  const float* b_ih  = (const float*)d_in[7];
  const float* b_hh  = (const float*)d_in[8];
  const float* W_kc  = (const float*)d_in[9];
  const float* W_qc  = (const float*)d_in[10];
  const float* W_vc  = (const float*)d_in[11];
  const float* W_att = (const float*)d_in[12];
  const float* b_att = (const float*)d_in[13];
  const float* W_val = (const float*)d_in[14];
  const float* b_val = (const float*)d_in[15];
  const float* W_dec = (const float*)d_in[16];
  const float* b_dec = (const float*)d_in[17];
  const float* W_mu  = (const float*)d_in[18];
  const float* b_mu  = (const float*)d_in[19];
  const float* W_sig = (const float*)d_in[20];
  const float* b_sig = (const float*)d_in[21];
  float* ws = (float*)d_ws;
  float* out = (float*)d_out;

  if (ws_size < (size_t)WS_FLOATS * sizeof(float)) return; // need ~106 MB scratch

  hipMemsetAsync(ws + OFF_E, 0, (size_t)Bb*Nn*Nn*sizeof(float), stream);
  k_precompute<<<1, 384, 0, stream>>>(W_se, b_se, W_ih, b_ih, W_vc, W_att, ws);
  k_gru<<<BN/4, 384, 0, stream>>>(x, W_init, b_init, W_hh, b_hh, ws);
  k_kqv<<<Bb*Tt, 256, 0, stream>>>(W_kc, W_qc, ws);
  k_attn<<<Bb*Hh*4, 256, 0, stream>>>(ws);
  k_decode<<<BN/4, 384, 0, stream>>>(x, W_hh, b_hh, W_val, b_val, ws);
  k_final<<<Bb*4, 256, 0, stream>>>(W_dec, b_dec, W_mu, b_mu, W_sig, b_sig, b_att, ws, out);
}

// Round 2
// 562.750 us; speedup vs baseline: 1.3538x; 1.3538x over previous
//
#include <hip/hip_runtime.h>
#include <math.h>

#define Bb 16
#define Tt 64
#define Nn 64
#define Ss 4
#define Dd 128
#define Hh 8
#define HD 16
#define BN 1024
#define G3 384   // 3*D

// workspace layout (in floats)
#define OFF_WX   0                              // 4*384
#define OFF_BX   1536                           // 384
#define OFF_U1   1920                           // 128*8
#define OFF_U2   2944                           // 128*8
#define OFF_YS   4096                           // T*BN*D
#define OFF_KK   (OFF_YS + Tt*BN*Dd)            // B*H*T*N*HD
#define OFF_QQ   (OFF_KK + Bb*Hh*Tt*Nn*HD)
#define OFF_VW1  (OFF_QQ + Bb*Hh*Tt*Nn*HD)      // B*H*T*N
#define OFF_VW2  (OFF_VW1 + Bb*Hh*Tt*Nn)
#define OFF_E    (OFF_VW2 + Bb*Hh*Tt*Nn)        // B*N*N
#define OFF_VV   (OFF_E + Bb*Nn*Nn)             // BN*D
#define WS_FLOATS (OFF_VV + BN*Dd)

__device__ __forceinline__ float fast_sigmoid(float v) {
  return 1.f / (1.f + __expf(-v));
}
__device__ __forceinline__ float fast_tanh(float v) {
  float e2 = __expf(2.f * v);
  return 1.f - 2.f / (e2 + 1.f);
}

// ---------------- kernel 0: fold weights ----------------
__global__ __launch_bounds__(384) void k_precompute(
    const float* __restrict__ W_se, const float* __restrict__ b_se,
    const float* __restrict__ W_ih, const float* __restrict__ b_ih,
    const float* __restrict__ W_vc, const float* __restrict__ W_att,
    float* __restrict__ ws) {
  const int c = threadIdx.x; // 0..383
  float* Wx = ws + OFF_WX; float* bx = ws + OFF_BX;
  float* u1 = ws + OFF_U1; float* u2 = ws + OFF_U2;
  float accb = b_ih[c];
  float a0 = 0.f, a1 = 0.f, a2 = 0.f, a3 = 0.f;
  for (int k = 0; k < Dd; ++k) {
    float w = W_ih[k*G3 + c];
    accb = fmaf(b_se[k], w, accb);
    a0 = fmaf(W_se[0*Dd + k], w, a0);
    a1 = fmaf(W_se[1*Dd + k], w, a1);
    a2 = fmaf(W_se[2*Dd + k], w, a2);
    a3 = fmaf(W_se[3*Dd + k], w, a3);
  }
  bx[c] = accb;
  Wx[0*G3 + c] = a0; Wx[1*G3 + c] = a1; Wx[2*G3 + c] = a2; Wx[3*G3 + c] = a3;
  for (int idx = c; idx < Dd*Hh; idx += 384) {
    int k = idx >> 3, h = idx & 7;
    float s1 = 0.f, s2 = 0.f;
    for (int d = 0; d < HD; ++d) {
      float v = W_vc[k*Dd + h*HD + d];
      s1 = fmaf(v, W_att[h*HD + d], s1);
      s2 = fmaf(v, W_att[Dd + h*HD + d], s2);
    }
    u1[k*Hh + h] = s1;
    u2[k*Hh + h] = s2;
  }
}

// ---------------- kernel 1: GRU, W_hh register-resident ----------------
// 2 rows/block, 512 blocks (2 blocks/CU, 12 waves/CU), thread c owns W_hh[:,c].
__global__ __launch_bounds__(384, 3) void k_gru(
    const float* __restrict__ x, const float* __restrict__ W_init,
    const float* __restrict__ b_init, const float* __restrict__ W_hh,
    const float* __restrict__ b_hh, float* __restrict__ ws) {
  __shared__ float h_lds[2][Dd];
  __shared__ float g_lds[2][4*Dd];   // [r|z|in|hn] per row
  __shared__ float xt_l[Tt+1][2][Ss];
  const int tid = threadIdx.x;
  const int blk = blockIdx.x;
  const int row0 = blk * 2;
  const int b = row0 >> 6;
  const int n0 = row0 & 63;
  float* ys = ws + OFF_YS;
  const float* Wx = ws + OFF_WX;
  const float* bxp = ws + OFF_BX;
  const int c = tid;

  // register-resident W_hh column c
  float W[Dd];
  #pragma unroll
  for (int k = 0; k < Dd; ++k) W[k] = W_hh[(size_t)k*G3 + c];

  // stage all x frames for our 2 rows: 65*2*4 = 520 floats
  for (int idx = tid; idx < (Tt+1)*2*Ss; idx += 384) {
    int t = idx >> 3, r = (idx >> 2) & 1, s = idx & 3;
    xt_l[t][r][s] = x[((size_t)(b*(Tt+1) + t)*Nn + (n0 + r))*Ss + s];
  }
  __syncthreads();

  // h0 = x[:,0] @ W_init + b_init  (256 threads: r=tid>>7, d=tid&127)
  if (tid < 2*Dd) {
    const int r = tid >> 7, d = tid & 127;
    float acc = b_init[d];
    #pragma unroll
    for (int s = 0; s < Ss; ++s) acc = fmaf(xt_l[0][r][s], W_init[s*Dd + d], acc);
    h_lds[r][d] = acc;
  }
  const float bhh = b_hh[c];
  const float wx0 = Wx[0*G3 + c], wx1 = Wx[1*G3 + c], wx2 = Wx[2*G3 + c], wx3 = Wx[3*G3 + c];
  const float bxv = bxp[c];
  __syncthreads();

  for (int t = 0; t < Tt; ++t) {
    float acc0 = bhh, acc1 = bhh;
    #pragma unroll
    for (int k4 = 0; k4 < Dd/4; ++k4) {
      float4 h0 = *(const float4*)&h_lds[0][k4*4];
      float4 h1 = *(const float4*)&h_lds[1][k4*4];
      acc0 = fmaf(h0.x, W[4*k4+0], acc0);
      acc0 = fmaf(h0.y, W[4*k4+1], acc0);
      acc0 = fmaf(h0.z, W[4*k4+2], acc0);
      acc0 = fmaf(h0.w, W[4*k4+3], acc0);
      acc1 = fmaf(h1.x, W[4*k4+0], acc1);
      acc1 = fmaf(h1.y, W[4*k4+1], acc1);
      acc1 = fmaf(h1.z, W[4*k4+2], acc1);
      acc1 = fmaf(h1.w, W[4*k4+3], acc1);
    }
    float gi0 = bxv, gi1 = bxv;
    gi0 = fmaf(xt_l[t][0][0], wx0, gi0);
    gi0 = fmaf(xt_l[t][0][1], wx1, gi0);
    gi0 = fmaf(xt_l[t][0][2], wx2, gi0);
    gi0 = fmaf(xt_l[t][0][3], wx3, gi0);
    gi1 = fmaf(xt_l[t][1][0], wx0, gi1);
    gi1 = fmaf(xt_l[t][1][1], wx1, gi1);
    gi1 = fmaf(xt_l[t][1][2], wx2, gi1);
    gi1 = fmaf(xt_l[t][1][3], wx3, gi1);
    if (c < 2*Dd) {
      g_lds[0][c] = acc0 + gi0;
      g_lds[1][c] = acc1 + gi1;
    } else {
      g_lds[0][c] = gi0; g_lds[0][c + Dd] = acc0;
      g_lds[1][c] = gi1; g_lds[1][c + Dd] = acc1;
    }
    __syncthreads();
    if (tid < 2*Dd) {
      const int r = tid >> 7, d = tid & 127;
      float rg = fast_sigmoid(g_lds[r][d]);
      float zg = fast_sigmoid(g_lds[r][Dd + d]);
      float ng = fast_tanh(fmaf(rg, g_lds[r][3*Dd + d], g_lds[r][2*Dd + d]));
      float hn = fmaf(zg, h_lds[r][d] - ng, ng);   // (1-z)*n + z*h
      h_lds[r][d] = hn;
      ys[(size_t)(t*BN + row0 + r)*Dd + d] = hn;
    }
    __syncthreads();
  }
}

// ---------------- kernel 2: k,q projections + vw scalars ----------------
__global__ __launch_bounds__(256) void k_kqv(
    const float* __restrict__ W_kc, const float* __restrict__ W_qc,
    float* __restrict__ ws) {
  __shared__ float ysl[64][Dd];  // 32KB
  const int tid = threadIdx.x;
  const int blk = blockIdx.x;    // b*T + t
  const int b = blk >> 6;
  const int t = blk & 63;
  const float* ysrc = ws + OFF_YS + (size_t)(t*BN + b*64)*Dd;
  for (int idx = tid; idx < 64*Dd; idx += 256) ((float*)ysl)[idx] = ysrc[idx];
  __syncthreads();

  const float* W = (tid < Dd) ? (W_kc + tid) : (W_qc + (tid - Dd));
  float acc[64];
  #pragma unroll
  for (int r = 0; r < 64; ++r) acc[r] = 0.f;
  for (int k = 0; k < Dd; k += 4) {
    float w0 = W[(k+0)*Dd];
    float w1 = W[(k+1)*Dd];
    float w2 = W[(k+2)*Dd];
    float w3 = W[(k+3)*Dd];
    #pragma unroll
    for (int r = 0; r < 64; ++r) {
      float4 hv = *(const float4*)&ysl[r][k];
      acc[r] = fmaf(hv.x, w0, acc[r]);
      acc[r] = fmaf(hv.y, w1, acc[r]);
      acc[r] = fmaf(hv.z, w2, acc[r]);
      acc[r] = fmaf(hv.w, w3, acc[r]);
    }
  }
  float* dst = ws + ((tid < Dd) ? OFF_KK : OFF_QQ);
  const int cc = tid & 127;
  const int h = cc >> 4, d = cc & 15;
  const size_t base = ((size_t)(b*Hh + h)*Tt + t)*(Nn*HD) + d;
  #pragma unroll
  for (int r = 0; r < 64; ++r) dst[base + (size_t)r*HD] = acc[r];

  const float* u1 = ws + OFF_U1;
  const float* u2 = ws + OFF_U2;
  for (int idx = tid; idx < 64*HD; idx += 256) {
    int r = idx >> 4, g = idx & 15, h2 = g >> 1, which = g & 1;
    const float* u = which ? u2 : u1;
    float s = 0.f;
    for (int k = 0; k < Dd; ++k) s = fmaf(ysl[r][k], u[k*Hh + h2], s);
    float* vw = ws + (which ? OFF_VW2 : OFF_VW1);
    vw[((size_t)(b*Hh + h2)*Tt + t)*Nn + r] = s;
  }
}

// ---------------- kernel 3: per-pair temporal online softmax -> e partials ----------------
__global__ __launch_bounds__(256) void k_attn(float* __restrict__ ws) {
  __shared__ float k_l[16*HD];
  __shared__ float q_l[HD*65];  // transposed, padded
  __shared__ float vw1_l[16], vw2_l[16];
  const int tid = threadIdx.x;
  const int blk = blockIdx.x;         // (b*H+h)*4 + quarter
  const int quarter = blk & 3;
  const int bh = blk >> 2;
  const int b = bh >> 3;
  const int i0 = quarter * 16;
  const float* kk = ws + OFF_KK + (size_t)bh*Tt*Nn*HD;
  const float* qq = ws + OFF_QQ + (size_t)bh*Tt*Nn*HD;
  const float* vw1 = ws + OFF_VW1 + (size_t)bh*Tt*Nn;
  const float* vw2 = ws + OFF_VW2 + (size_t)bh*Tt*Nn;
  float* e = ws + OFF_E + (size_t)b*Nn*Nn;
  const int j = tid & 63, wq = tid >> 6;
  float m[4], Ssum[4], A1[4], A2[4];
  #pragma unroll
  for (int p = 0; p < 4; ++p) { m[p] = -1e30f; Ssum[p] = 0.f; A1[p] = 0.f; A2[p] = 0.f; }
  const float scale = 0.08838834764831845f; // 1/sqrt(128)

  for (int t = 0; t < Tt; ++t) {
    __syncthreads();
    k_l[tid] = kk[(size_t)t*Nn*HD + i0*HD + tid];
    for (int idx = tid; idx < Nn*HD; idx += 256) {
      int jj = idx >> 4, d = idx & 15;
      q_l[d*65 + jj] = qq[(size_t)t*Nn*HD + idx];
    }
    if (tid < 16) vw1_l[tid] = vw1[(size_t)t*Nn + i0 + tid];
    else if (tid < 32) vw2_l[tid - 16] = vw2[(size_t)t*Nn + i0 + tid - 16];
    __syncthreads();
    float qr[16];
    #pragma unroll
    for (int d = 0; d < 16; ++d) qr[d] = q_l[d*65 + j];
    #pragma unroll
    for (int p = 0; p < 4; ++p) {
      const int il = wq + 4*p;
      float s = 0.f;
      #pragma unroll
      for (int d = 0; d < 16; ++d) s = fmaf(qr[d], k_l[il*HD + d], s);
      s *= scale;
      float mn = fmaxf(m[p], s);
      float cc = __expf(m[p] - mn);
      float pp = __expf(s - mn);
      Ssum[p] = fmaf(Ssum[p], cc, pp);
      A1[p] = fmaf(A1[p], cc, pp * vw1_l[il]);
      A2[p] = fmaf(A2[p], cc, pp * vw2_l[il]);
      m[p] = mn;
    }
  }
  #pragma unroll
  for (int p = 0; p < 4; ++p) {
    const int i = i0 + wq + 4*p;
    float inv = 1.f / Ssum[p];
    atomicAdd(&e[i*Nn + j], A1[p] * inv);
    atomicAdd(&e[j*Nn + i], A2[p] * inv);
  }
}

// ---------------- kernel 4: decode GRU step + vv ----------------
__global__ __launch_bounds__(384) void k_decode(
    const float* __restrict__ x, const float* __restrict__ W_hh,
    const float* __restrict__ b_hh, const float* __restrict__ W_val,
    const float* __restrict__ b_val, float* __restrict__ ws) {
  __shared__ float h_lds[4][Dd];
  __shared__ float g_lds[4][4*Dd];
  __shared__ float xt[4][Ss];
  const int tid = threadIdx.x;
  const int blk = blockIdx.x;
  const int row0 = blk * 4;
  const int b = row0 >> 6;
  const int n0 = row0 & 63;
  const float* ys = ws + OFF_YS;
  const float* Wx = ws + OFF_WX;
  const float* bxp = ws + OFF_BX;
  if (tid < Dd) {
    for (int r = 0; r < 4; ++r)
      h_lds[r][tid] = ys[(size_t)((Tt-1)*BN + row0 + r)*Dd + tid];
  }
  if (tid >= 320 && tid < 336) {
    int q = tid - 320; int r = q >> 2, s = q & 3;
    xt[r][s] = x[((size_t)(b*(Tt+1) + Tt)*Nn + (n0 + r))*Ss + s];
  }
  const int c = tid;
  const float bhh = b_hh[c];
  const float wx0 = Wx[0*G3 + c], wx1 = Wx[1*G3 + c], wx2 = Wx[2*G3 + c], wx3 = Wx[3*G3 + c];
  const float bxv = bxp[c];
  __syncthreads();
  float acc[4] = {bhh, bhh, bhh, bhh};
  for (int k = 0; k < Dd; k += 4) {
    float w0 = W_hh[(k+0)*G3 + c];
    float w1 = W_hh[(k+1)*G3 + c];
    float w2 = W_hh[(k+2)*G3 + c];
    float w3 = W_hh[(k+3)*G3 + c];
    #pragma unroll
    for (int r = 0; r < 4; ++r) {
      float4 hv = *(const float4*)&h_lds[r][k];
      acc[r] = fmaf(hv.x, w0, acc[r]);
      acc[r] = fmaf(hv.y, w1, acc[r]);
      acc[r] = fmaf(hv.z, w2, acc[r]);
      acc[r] = fmaf(hv.w, w3, acc[r]);
    }
  }
  float gi[4];
  #pragma unroll
  for (int r = 0; r < 4; ++r) {
    float g = bxv;
    g = fmaf(xt[r][0], wx0, g);
    g = fmaf(xt[r][1], wx1, g);
    g = fmaf(xt[r][2], wx2, g);
    g = fmaf(xt[r][3], wx3, g);
    gi[r] = g;
  }
  if (c < 2*Dd) {
    #pragma unroll
    for (int r = 0; r < 4; ++r) g_lds[r][c] = acc[r] + gi[r];
  } else {
    #pragma unroll
    for (int r = 0; r < 4; ++r) { g_lds[r][c] = gi[r]; g_lds[r][c + Dd] = acc[r]; }
  }
  __syncthreads();
  if (tid < Dd) {
    const int d = tid;
    #pragma unroll
    for (int r = 0; r < 4; ++r) {
      float rg = fast_sigmoid(g_lds[r][d]);
      float zg = fast_sigmoid(g_lds[r][Dd + d]);
      float ng = fast_tanh(fmaf(rg, g_lds[r][3*Dd + d], g_lds[r][2*Dd + d]));
      float hn = fmaf(zg, h_lds[r][d] - ng, ng);
      h_lds[r][d] = hn;
    }
  }
  __syncthreads();
  if (tid < Dd) {
    const int c2 = tid;
    for (int r = 0; r < 4; ++r) {
      float a = b_val[c2];
      for (int k = 0; k < Dd; k += 4) {
        float4 hv = *(const float4*)&h_lds[r][k];
        a = fmaf(hv.x, W_val[(k+0)*Dd + c2], a);
        a = fmaf(hv.y, W_val[(k+1)*Dd + c2], a);
        a = fmaf(hv.z, W_val[(k+2)*Dd + c2], a);
        a = fmaf(hv.w, W_val[(k+3)*Dd + c2], a);
      }
      ws[OFF_VV + (size_t)(row0 + r)*Dd + c2] = a;
    }
  }
}

// ---------------- kernel 5: weight/p/dec/mu/sig ----------------
__global__ __launch_bounds__(256) void k_final(
    const float* __restrict__ W_dec, const float* __restrict__ b_dec,
    const float* __restrict__ W_mu, const float* __restrict__ b_mu,
    const float* __restrict__ W_sig, const float* __restrict__ b_sig,
    const float* __restrict__ b_att, float* __restrict__ ws,
    float* __restrict__ out) {
  __shared__ float vvl[64][Dd];  // 32KB
  __shared__ float wl[16][64];
  __shared__ float pl[16][Dd];
  __shared__ float ddl[16][Dd];
  const int tid = threadIdx.x;
  const int blk = blockIdx.x;
  const int b = blk >> 2, iq = blk & 3, i0 = iq*16;
  const float* vv = ws + OFF_VV + (size_t)b*64*Dd;
  const float* e = ws + OFF_E + (size_t)b*Nn*Nn;
  const float batt = b_att[0];
  for (int idx = tid; idx < 64*Dd; idx += 256) ((float*)vvl)[idx] = vv[idx];
  for (int idx = tid; idx < 16*64; idx += 256) {
    int il = idx >> 6, jj = idx & 63;
    int i = i0 + il;
    wl[il][jj] = (i == jj) ? 0.f : fast_tanh(e[i*Nn + jj] + batt + 0.5f);
  }
  __syncthreads();
  {
    const int d = tid & 127, ih = tid >> 7;
    #pragma unroll
    for (int kk2 = 0; kk2 < 8; ++kk2) {
      int il = ih*8 + kk2;
      float a = 0.f;
      for (int jj = 0; jj < 64; ++jj) a = fmaf(wl[il][jj], vvl[jj][d], a);
      pl[il][d] = a * (1.f/64.f);
    }
  }
  __syncthreads();
  {
    const int e2 = tid & 127, ih = tid >> 7;
    #pragma unroll
    for (int kk2 = 0; kk2 < 8; ++kk2) {
      int il = ih*8 + kk2;
      float a = b_dec[e2];
      for (int c2 = 0; c2 < Dd; ++c2) a = fmaf(vvl[i0 + il][c2], W_dec[c2*Dd + e2], a);
      for (int c2 = 0; c2 < Dd; ++c2) a = fmaf(pl[il][c2], W_dec[(Dd + c2)*Dd + e2], a);
      ddl[il][e2] = a;
    }
  }
  __syncthreads();
  if (tid < 128) {
    const int il = tid >> 3, g = tid & 7, which = g >> 2, s = g & 3;
    const float* W = which ? W_sig : W_mu;
    float a = which ? b_sig[s] : b_mu[s];
    for (int k = 0; k < Dd; ++k) a = fmaf(ddl[il][k], W[k*Ss + s], a);
    if (which) a = 1.f/(1.f + __expf(-a)) + 1e-6f;
    out[(size_t)which*(Bb*Nn*Ss) + (size_t)(b*64 + i0 + il)*Ss + s] = a;
  }
}

extern "C" void kernel_launch(void* const* d_in, const int* in_sizes, int n_in,
                              void* d_out, int out_size, void* d_ws, size_t ws_size,
                              hipStream_t stream) {
  const float* x     = (const float*)d_in[0];
  const float* W_se  = (const float*)d_in[1];
  const float* b_se  = (const float*)d_in[2];
  const float* W_init= (const float*)d_in[3];
  const float* b_init= (const float*)d_in[4];
  const float* W_ih  = (const float*)d_in[5];
  const float* W_hh  = (const float*)d_in[6];
  const float* b_ih  = (const float*)d_in[7];
  const float* b_hh  = (const float*)d_in[8];
  const float* W_kc  = (const float*)d_in[9];
  const float* W_qc  = (const float*)d_in[10];
  const float* W_vc  = (const float*)d_in[11];
  const float* W_att = (const float*)d_in[12];
  const float* b_att = (const float*)d_in[13];
  const float* W_val = (const float*)d_in[14];
  const float* b_val = (const float*)d_in[15];
  const float* W_dec = (const float*)d_in[16];
  const float* b_dec = (const float*)d_in[17];
  const float* W_mu  = (const float*)d_in[18];
  const float* b_mu  = (const float*)d_in[19];
  const float* W_sig = (const float*)d_in[20];
  const float* b_sig = (const float*)d_in[21];
  float* ws = (float*)d_ws;
  float* out = (float*)d_out;

  if (ws_size < (size_t)WS_FLOATS * sizeof(float)) return;

  hipMemsetAsync(ws + OFF_E, 0, (size_t)Bb*Nn*Nn*sizeof(float), stream);
  k_precompute<<<1, 384, 0, stream>>>(W_se, b_se, W_ih, b_ih, W_vc, W_att, ws);
  k_gru<<<BN/2, 384, 0, stream>>>(x, W_init, b_init, W_hh, b_hh, ws);
  k_kqv<<<Bb*Tt, 256, 0, stream>>>(W_kc, W_qc, ws);
  k_attn<<<Bb*Hh*4, 256, 0, stream>>>(ws);
  k_decode<<<BN/4, 384, 0, stream>>>(x, W_hh, b_hh, W_val, b_val, ws);
  k_final<<<Bb*4, 256, 0, stream>>>(W_dec, b_dec, W_mu, b_mu, W_sig, b_sig, b_att, ws, out);
}

// Round 3
// 559.324 us; speedup vs baseline: 1.3621x; 1.0061x over previous
//
#include <hip/hip_runtime.h>
#include <math.h>

#define Bb 16
#define Tt 64
#define Nn 64
#define Ss 4
#define Dd 128
#define Hh 8
#define HD 16
#define BN 1024
#define G3 384   // 3*D

// workspace layout (in floats)
#define OFF_WX   0                              // 4*384
#define OFF_BX   1536                           // 384
#define OFF_U1   1920                           // 128*8
#define OFF_U2   2944                           // 128*8
#define OFF_YS   4096                           // T*BN*D
#define OFF_KK   (OFF_YS + Tt*BN*Dd)            // B*H*T*N*HD
#define OFF_QQ   (OFF_KK + Bb*Hh*Tt*Nn*HD)
#define OFF_VW1  (OFF_QQ + Bb*Hh*Tt*Nn*HD)      // B*H*T*N
#define OFF_VW2  (OFF_VW1 + Bb*Hh*Tt*Nn)
#define OFF_E    (OFF_VW2 + Bb*Hh*Tt*Nn)        // B*N*N
#define OFF_VV   (OFF_E + Bb*Nn*Nn)             // BN*D
#define WS_FLOATS (OFF_VV + BN*Dd)
// transient: transposed W_hh lives in the (not yet written) KK region during k_gru
#define OFF_WT   OFF_KK                         // 384*128 floats

__device__ __forceinline__ float fast_sigmoid(float v) {
  return 1.f / (1.f + __expf(-v));
}
__device__ __forceinline__ float fast_tanh(float v) {
  float e2 = __expf(2.f * v);
  return 1.f - 2.f / (e2 + 1.f);
}

// ---------------- kernel 0: fold weights + transpose W_hh ----------------
// block 0: fold W_se@W_ih, b fold, u1/u2; blocks 1..48: transpose 8 cols each
__global__ __launch_bounds__(384) void k_precompute(
    const float* __restrict__ W_se, const float* __restrict__ b_se,
    const float* __restrict__ W_ih, const float* __restrict__ b_ih,
    const float* __restrict__ W_hh,
    const float* __restrict__ W_vc, const float* __restrict__ W_att,
    float* __restrict__ ws) {
  const int tid = threadIdx.x;
  if (blockIdx.x > 0) {
    // transpose slice: columns c0..c0+7 of W_hh -> WT[c][k]
    const int c0 = (blockIdx.x - 1) * 8;
    float* WT = ws + OFF_WT;
    for (int idx = tid; idx < 8*Dd; idx += 384) {
      int cl = idx >> 7, k = idx & 127;
      WT[(size_t)(c0 + cl)*Dd + k] = W_hh[(size_t)k*G3 + c0 + cl];
    }
    return;
  }
  const int c = tid; // 0..383
  float* Wx = ws + OFF_WX; float* bx = ws + OFF_BX;
  float* u1 = ws + OFF_U1; float* u2 = ws + OFF_U2;
  float accb = b_ih[c];
  float a0 = 0.f, a1 = 0.f, a2 = 0.f, a3 = 0.f;
  for (int k = 0; k < Dd; ++k) {
    float w = W_ih[k*G3 + c];
    accb = fmaf(b_se[k], w, accb);
    a0 = fmaf(W_se[0*Dd + k], w, a0);
    a1 = fmaf(W_se[1*Dd + k], w, a1);
    a2 = fmaf(W_se[2*Dd + k], w, a2);
    a3 = fmaf(W_se[3*Dd + k], w, a3);
  }
  bx[c] = accb;
  Wx[0*G3 + c] = a0; Wx[1*G3 + c] = a1; Wx[2*G3 + c] = a2; Wx[3*G3 + c] = a3;
  for (int idx = c; idx < Dd*Hh; idx += 384) {
    int k = idx >> 3, h = idx & 7;
    float s1 = 0.f, s2 = 0.f;
    for (int d = 0; d < HD; ++d) {
      float v = W_vc[k*Dd + h*HD + d];
      s1 = fmaf(v, W_att[h*HD + d], s1);
      s2 = fmaf(v, W_att[Dd + h*HD + d], s2);
    }
    u1[k*Hh + h] = s1;
    u2[k*Hh + h] = s2;
  }
}

// ---------------- kernel 1: GRU, W_hh truly register-resident ----------------
// 4 rows/block, 256 blocks (1 block/CU, single pass). Thread c owns WT[c][:]
// as float4 Wr[32] (128 VGPRs). launch_bounds(384,2) -> 256 VGPR cap.
__global__ __launch_bounds__(384, 2) void k_gru(
    const float* __restrict__ x, const float* __restrict__ W_init,
    const float* __restrict__ b_init,
    const float* __restrict__ b_hh, float* __restrict__ ws) {
  __shared__ float h_lds[4][Dd];
  __shared__ float g_lds[4][4*Dd];   // [r|z|in|hn] per row
  __shared__ float xt_l[Tt+1][4][Ss];
  const int tid = threadIdx.x;
  const int blk = blockIdx.x;
  const int row0 = blk * 4;
  const int b = row0 >> 6;
  const int n0 = row0 & 63;
  float* ys = ws + OFF_YS;
  const float* Wx = ws + OFF_WX;
  const float* bxp = ws + OFF_BX;
  const int c = tid;

  // register-resident W_hh column c (contiguous after transpose)
  const float4* wtp = (const float4*)(ws + OFF_WT + (size_t)c*Dd);
  float4 Wr[32];
  #pragma unroll
  for (int i = 0; i < 32; ++i) Wr[i] = wtp[i];

  // stage all x frames for our 4 rows: 65*4*4 = 1040 floats
  for (int idx = tid; idx < (Tt+1)*4*Ss; idx += 384) {
    int t = idx >> 4, r = (idx >> 2) & 3, s = idx & 3;
    xt_l[t][r][s] = x[((size_t)(b*(Tt+1) + t)*Nn + (n0 + r))*Ss + s];
  }
  __syncthreads();

  // h0 = x[:,0] @ W_init + b_init
  if (tid < Dd) {
    const int d = tid;
    #pragma unroll
    for (int r = 0; r < 4; ++r) {
      float acc = b_init[d];
      #pragma unroll
      for (int s = 0; s < Ss; ++s) acc = fmaf(xt_l[0][r][s], W_init[s*Dd + d], acc);
      h_lds[r][d] = acc;
    }
  }
  const float bhh = b_hh[c];
  const float wx0 = Wx[0*G3 + c], wx1 = Wx[1*G3 + c], wx2 = Wx[2*G3 + c], wx3 = Wx[3*G3 + c];
  const float bxv = bxp[c];
  __syncthreads();

  for (int t = 0; t < Tt; ++t) {
    float acc0 = bhh, acc1 = bhh, acc2 = bhh, acc3 = bhh;
    #pragma unroll
    for (int k4 = 0; k4 < Dd/4; ++k4) {
      float4 w = Wr[k4];
      float4 h0 = *(const float4*)&h_lds[0][k4*4];
      float4 h1 = *(const float4*)&h_lds[1][k4*4];
      float4 h2 = *(const float4*)&h_lds[2][k4*4];
      float4 h3 = *(const float4*)&h_lds[3][k4*4];
      acc0 = fmaf(h0.x, w.x, acc0); acc0 = fmaf(h0.y, w.y, acc0);
      acc0 = fmaf(h0.z, w.z, acc0); acc0 = fmaf(h0.w, w.w, acc0);
      acc1 = fmaf(h1.x, w.x, acc1); acc1 = fmaf(h1.y, w.y, acc1);
      acc1 = fmaf(h1.z, w.z, acc1); acc1 = fmaf(h1.w, w.w, acc1);
      acc2 = fmaf(h2.x, w.x, acc2); acc2 = fmaf(h2.y, w.y, acc2);
      acc2 = fmaf(h2.z, w.z, acc2); acc2 = fmaf(h2.w, w.w, acc2);
      acc3 = fmaf(h3.x, w.x, acc3); acc3 = fmaf(h3.y, w.y, acc3);
      acc3 = fmaf(h3.z, w.z, acc3); acc3 = fmaf(h3.w, w.w, acc3);
    }
    float gi[4];
    #pragma unroll
    for (int r = 0; r < 4; ++r) {
      float g = bxv;
      g = fmaf(xt_l[t][r][0], wx0, g);
      g = fmaf(xt_l[t][r][1], wx1, g);
      g = fmaf(xt_l[t][r][2], wx2, g);
      g = fmaf(xt_l[t][r][3], wx3, g);
      gi[r] = g;
    }
    float accs[4] = {acc0, acc1, acc2, acc3};
    if (c < 2*Dd) {
      #pragma unroll
      for (int r = 0; r < 4; ++r) g_lds[r][c] = accs[r] + gi[r];
    } else {
      #pragma unroll
      for (int r = 0; r < 4; ++r) { g_lds[r][c] = gi[r]; g_lds[r][c + Dd] = accs[r]; }
    }
    __syncthreads();
    if (tid < 2*Dd) {
      const int d = tid & 127;
      #pragma unroll
      for (int rr = 0; rr < 2; ++rr) {
        const int r = (tid >> 7)*2 + rr;
        float rg = fast_sigmoid(g_lds[r][d]);
        float zg = fast_sigmoid(g_lds[r][Dd + d]);
        float ng = fast_tanh(fmaf(rg, g_lds[r][3*Dd + d], g_lds[r][2*Dd + d]));
        float hn = fmaf(zg, h_lds[r][d] - ng, ng);   // (1-z)*n + z*h
        h_lds[r][d] = hn;
        ys[(size_t)(t*BN + row0 + r)*Dd + d] = hn;
      }
    }
    __syncthreads();
  }
}

// ---------------- kernel 2: k,q projections + vw scalars ----------------
__global__ __launch_bounds__(256) void k_kqv(
    const float* __restrict__ W_kc, const float* __restrict__ W_qc,
    float* __restrict__ ws) {
  __shared__ float ysl[64][Dd];  // 32KB
  const int tid = threadIdx.x;
  const int blk = blockIdx.x;    // b*T + t
  const int b = blk >> 6;
  const int t = blk & 63;
  const float* ysrc = ws + OFF_YS + (size_t)(t*BN + b*64)*Dd;
  for (int idx = tid; idx < 64*Dd; idx += 256) ((float*)ysl)[idx] = ysrc[idx];
  __syncthreads();

  const float* W = (tid < Dd) ? (W_kc + tid) : (W_qc + (tid - Dd));
  float acc[64];
  #pragma unroll
  for (int r = 0; r < 64; ++r) acc[r] = 0.f;
  for (int k = 0; k < Dd; k += 4) {
    float w0 = W[(k+0)*Dd];
    float w1 = W[(k+1)*Dd];
    float w2 = W[(k+2)*Dd];
    float w3 = W[(k+3)*Dd];
    #pragma unroll
    for (int r = 0; r < 64; ++r) {
      float4 hv = *(const float4*)&ysl[r][k];
      acc[r] = fmaf(hv.x, w0, acc[r]);
      acc[r] = fmaf(hv.y, w1, acc[r]);
      acc[r] = fmaf(hv.z, w2, acc[r]);
      acc[r] = fmaf(hv.w, w3, acc[r]);
    }
  }
  float* dst = ws + ((tid < Dd) ? OFF_KK : OFF_QQ);
  const int cc = tid & 127;
  const int h = cc >> 4, d = cc & 15;
  const size_t base = ((size_t)(b*Hh + h)*Tt + t)*(Nn*HD) + d;
  #pragma unroll
  for (int r = 0; r < 64; ++r) dst[base + (size_t)r*HD] = acc[r];

  const float* u1 = ws + OFF_U1;
  const float* u2 = ws + OFF_U2;
  for (int idx = tid; idx < 64*HD; idx += 256) {
    int r = idx >> 4, g = idx & 15, h2 = g >> 1, which = g & 1;
    const float* u = which ? u2 : u1;
    float s = 0.f;
    for (int k = 0; k < Dd; ++k) s = fmaf(ysl[r][k], u[k*Hh + h2], s);
    float* vw = ws + (which ? OFF_VW2 : OFF_VW1);
    vw[((size_t)(b*Hh + h2)*Tt + t)*Nn + r] = s;
  }
}

// ---------------- kernel 3: per-pair temporal online softmax -> e partials ----------------
__global__ __launch_bounds__(256) void k_attn(float* __restrict__ ws) {
  __shared__ float k_l[16*HD];
  __shared__ float q_l[HD*65];  // transposed, padded
  __shared__ float vw1_l[16], vw2_l[16];
  const int tid = threadIdx.x;
  const int blk = blockIdx.x;         // (b*H+h)*4 + quarter
  const int quarter = blk & 3;
  const int bh = blk >> 2;
  const int b = bh >> 3;
  const int i0 = quarter * 16;
  const float* kk = ws + OFF_KK + (size_t)bh*Tt*Nn*HD;
  const float* qq = ws + OFF_QQ + (size_t)bh*Tt*Nn*HD;
  const float* vw1 = ws + OFF_VW1 + (size_t)bh*Tt*Nn;
  const float* vw2 = ws + OFF_VW2 + (size_t)bh*Tt*Nn;
  float* e = ws + OFF_E + (size_t)b*Nn*Nn;
  const int j = tid & 63, wq = tid >> 6;
  float m[4], Ssum[4], A1[4], A2[4];
  #pragma unroll
  for (int p = 0; p < 4; ++p) { m[p] = -1e30f; Ssum[p] = 0.f; A1[p] = 0.f; A2[p] = 0.f; }
  const float scale = 0.08838834764831845f; // 1/sqrt(128)

  for (int t = 0; t < Tt; ++t) {
    __syncthreads();
    k_l[tid] = kk[(size_t)t*Nn*HD + i0*HD + tid];
    for (int idx = tid; idx < Nn*HD; idx += 256) {
      int jj = idx >> 4, d = idx & 15;
      q_l[d*65 + jj] = qq[(size_t)t*Nn*HD + idx];
    }
    if (tid < 16) vw1_l[tid] = vw1[(size_t)t*Nn + i0 + tid];
    else if (tid < 32) vw2_l[tid - 16] = vw2[(size_t)t*Nn + i0 + tid - 16];
    __syncthreads();
    float qr[16];
    #pragma unroll
    for (int d = 0; d < 16; ++d) qr[d] = q_l[d*65 + j];
    #pragma unroll
    for (int p = 0; p < 4; ++p) {
      const int il = wq + 4*p;
      float s = 0.f;
      #pragma unroll
      for (int d = 0; d < 16; ++d) s = fmaf(qr[d], k_l[il*HD + d], s);
      s *= scale;
      float mn = fmaxf(m[p], s);
      float cc = __expf(m[p] - mn);
      float pp = __expf(s - mn);
      Ssum[p] = fmaf(Ssum[p], cc, pp);
      A1[p] = fmaf(A1[p], cc, pp * vw1_l[il]);
      A2[p] = fmaf(A2[p], cc, pp * vw2_l[il]);
      m[p] = mn;
    }
  }
  #pragma unroll
  for (int p = 0; p < 4; ++p) {
    const int i = i0 + wq + 4*p;
    float inv = 1.f / Ssum[p];
    atomicAdd(&e[i*Nn + j], A1[p] * inv);
    atomicAdd(&e[j*Nn + i], A2[p] * inv);
  }
}

// ---------------- kernel 4: decode GRU step + vv ----------------
__global__ __launch_bounds__(384) void k_decode(
    const float* __restrict__ x, const float* __restrict__ W_hh,
    const float* __restrict__ b_hh, const float* __restrict__ W_val,
    const float* __restrict__ b_val, float* __restrict__ ws) {
  __shared__ float h_lds[4][Dd];
  __shared__ float g_lds[4][4*Dd];
  __shared__ float xt[4][Ss];
  const int tid = threadIdx.x;
  const int blk = blockIdx.x;
  const int row0 = blk * 4;
  const int b = row0 >> 6;
  const int n0 = row0 & 63;
  const float* ys = ws + OFF_YS;
  const float* Wx = ws + OFF_WX;
  const float* bxp = ws + OFF_BX;
  if (tid < Dd) {
    for (int r = 0; r < 4; ++r)
      h_lds[r][tid] = ys[(size_t)((Tt-1)*BN + row0 + r)*Dd + tid];
  }
  if (tid >= 320 && tid < 336) {
    int q = tid - 320; int r = q >> 2, s = q & 3;
    xt[r][s] = x[((size_t)(b*(Tt+1) + Tt)*Nn + (n0 + r))*Ss + s];
  }
  const int c = tid;
  const float bhh = b_hh[c];
  const float wx0 = Wx[0*G3 + c], wx1 = Wx[1*G3 + c], wx2 = Wx[2*G3 + c], wx3 = Wx[3*G3 + c];
  const float bxv = bxp[c];
  __syncthreads();
  float acc[4] = {bhh, bhh, bhh, bhh};
  for (int k = 0; k < Dd; k += 4) {
    float w0 = W_hh[(k+0)*G3 + c];
    float w1 = W_hh[(k+1)*G3 + c];
    float w2 = W_hh[(k+2)*G3 + c];
    float w3 = W_hh[(k+3)*G3 + c];
    #pragma unroll
    for (int r = 0; r < 4; ++r) {
      float4 hv = *(const float4*)&h_lds[r][k];
      acc[r] = fmaf(hv.x, w0, acc[r]);
      acc[r] = fmaf(hv.y, w1, acc[r]);
      acc[r] = fmaf(hv.z, w2, acc[r]);
      acc[r] = fmaf(hv.w, w3, acc[r]);
    }
  }
  float gi[4];
  #pragma unroll
  for (int r = 0; r < 4; ++r) {
    float g = bxv;
    g = fmaf(xt[r][0], wx0, g);
    g = fmaf(xt[r][1], wx1, g);
    g = fmaf(xt[r][2], wx2, g);
    g = fmaf(xt[r][3], wx3, g);
    gi[r] = g;
  }
  if (c < 2*Dd) {
    #pragma unroll
    for (int r = 0; r < 4; ++r) g_lds[r][c] = acc[r] + gi[r];
  } else {
    #pragma unroll
    for (int r = 0; r < 4; ++r) { g_lds[r][c] = gi[r]; g_lds[r][c + Dd] = acc[r]; }
  }
  __syncthreads();
  if (tid < Dd) {
    const int d = tid;
    #pragma unroll
    for (int r = 0; r < 4; ++r) {
      float rg = fast_sigmoid(g_lds[r][d]);
      float zg = fast_sigmoid(g_lds[r][Dd + d]);
      float ng = fast_tanh(fmaf(rg, g_lds[r][3*Dd + d], g_lds[r][2*Dd + d]));
      float hn = fmaf(zg, h_lds[r][d] - ng, ng);
      h_lds[r][d] = hn;
    }
  }
  __syncthreads();
  if (tid < Dd) {
    const int c2 = tid;
    for (int r = 0; r < 4; ++r) {
      float a = b_val[c2];
      for (int k = 0; k < Dd; k += 4) {
        float4 hv = *(const float4*)&h_lds[r][k];
        a = fmaf(hv.x, W_val[(k+0)*Dd + c2], a);
        a = fmaf(hv.y, W_val[(k+1)*Dd + c2], a);
        a = fmaf(hv.z, W_val[(k+2)*Dd + c2], a);
        a = fmaf(hv.w, W_val[(k+3)*Dd + c2], a);
      }
      ws[OFF_VV + (size_t)(row0 + r)*Dd + c2] = a;
    }
  }
}

// ---------------- kernel 5: weight/p/dec/mu/sig ----------------
__global__ __launch_bounds__(256) void k_final(
    const float* __restrict__ W_dec, const float* __restrict__ b_dec,
    const float* __restrict__ W_mu, const float* __restrict__ b_mu,
    const float* __restrict__ W_sig, const float* __restrict__ b_sig,
    const float* __restrict__ b_att, float* __restrict__ ws,
    float* __restrict__ out) {
  __shared__ float vvl[64][Dd];  // 32KB
  __shared__ float wl[16][64];
  __shared__ float pl[16][Dd];
  __shared__ float ddl[16][Dd];
  const int tid = threadIdx.x;
  const int blk = blockIdx.x;
  const int b = blk >> 2, iq = blk & 3, i0 = iq*16;
  const float* vv = ws + OFF_VV + (size_t)b*64*Dd;
  const float* e = ws + OFF_E + (size_t)b*Nn*Nn;
  const float batt = b_att[0];
  for (int idx = tid; idx < 64*Dd; idx += 256) ((float*)vvl)[idx] = vv[idx];
  for (int idx = tid; idx < 16*64; idx += 256) {
    int il = idx >> 6, jj = idx & 63;
    int i = i0 + il;
    wl[il][jj] = (i == jj) ? 0.f : fast_tanh(e[i*Nn + jj] + batt + 0.5f);
  }
  __syncthreads();
  {
    const int d = tid & 127, ih = tid >> 7;
    #pragma unroll
    for (int kk2 = 0; kk2 < 8; ++kk2) {
      int il = ih*8 + kk2;
      float a = 0.f;
      for (int jj = 0; jj < 64; ++jj) a = fmaf(wl[il][jj], vvl[jj][d], a);
      pl[il][d] = a * (1.f/64.f);
    }
  }
  __syncthreads();
  {
    const int e2 = tid & 127, ih = tid >> 7;
    #pragma unroll
    for (int kk2 = 0; kk2 < 8; ++kk2) {
      int il = ih*8 + kk2;
      float a = b_dec[e2];
      for (int c2 = 0; c2 < Dd; ++c2) a = fmaf(vvl[i0 + il][c2], W_dec[c2*Dd + e2], a);
      for (int c2 = 0; c2 < Dd; ++c2) a = fmaf(pl[il][c2], W_dec[(Dd + c2)*Dd + e2], a);
      ddl[il][e2] = a;
    }
  }
  __syncthreads();
  if (tid < 128) {
    const int il = tid >> 3, g = tid & 7, which = g >> 2, s = g & 3;
    const float* W = which ? W_sig : W_mu;
    float a = which ? b_sig[s] : b_mu[s];
    for (int k = 0; k < Dd; ++k) a = fmaf(ddl[il][k], W[k*Ss + s], a);
    if (which) a = 1.f/(1.f + __expf(-a)) + 1e-6f;
    out[(size_t)which*(Bb*Nn*Ss) + (size_t)(b*64 + i0 + il)*Ss + s] = a;
  }
}

extern "C" void kernel_launch(void* const* d_in, const int* in_sizes, int n_in,
                              void* d_out, int out_size, void* d_ws, size_t ws_size,
                              hipStream_t stream) {
  const float* x     = (const float*)d_in[0];
  const float* W_se  = (const float*)d_in[1];
  const float* b_se  = (const float*)d_in[2];
  const float* W_init= (const float*)d_in[3];
  const float* b_init= (const float*)d_in[4];
  const float* W_ih  = (const float*)d_in[5];
  const float* W_hh  = (const float*)d_in[6];
  const float* b_ih  = (const float*)d_in[7];
  const float* b_hh  = (const float*)d_in[8];
  const float* W_kc  = (const float*)d_in[9];
  const float* W_qc  = (const float*)d_in[10];
  const float* W_vc  = (const float*)d_in[11];
  const float* W_att = (const float*)d_in[12];
  const float* b_att = (const float*)d_in[13];
  const float* W_val = (const float*)d_in[14];
  const float* b_val = (const float*)d_in[15];
  const float* W_dec = (const float*)d_in[16];
  const float* b_dec = (const float*)d_in[17];
  const float* W_mu  = (const float*)d_in[18];
  const float* b_mu  = (const float*)d_in[19];
  const float* W_sig = (const float*)d_in[20];
  const float* b_sig = (const float*)d_in[21];
  float* ws = (float*)d_ws;
  float* out = (float*)d_out;

  if (ws_size < (size_t)WS_FLOATS * sizeof(float)) return;

  hipMemsetAsync(ws + OFF_E, 0, (size_t)Bb*Nn*Nn*sizeof(float), stream);
  k_precompute<<<49, 384, 0, stream>>>(W_se, b_se, W_ih, b_ih, W_hh, W_vc, W_att, ws);
  k_gru<<<BN/4, 384, 0, stream>>>(x, W_init, b_init, b_hh, ws);
  k_kqv<<<Bb*Tt, 256, 0, stream>>>(W_kc, W_qc, ws);
  k_attn<<<Bb*Hh*4, 256, 0, stream>>>(ws);
  k_decode<<<BN/4, 384, 0, stream>>>(x, W_hh, b_hh, W_val, b_val, ws);
  k_final<<<Bb*4, 256, 0, stream>>>(W_dec, b_dec, W_mu, b_mu, W_sig, b_sig, b_att, ws, out);
}

// Round 4
// 529.246 us; speedup vs baseline: 1.4395x; 1.0568x over previous
//
#include <hip/hip_runtime.h>
#include <math.h>

#define Bb 16
#define Tt 64
#define Nn 64
#define Ss 4
#define Dd 128
#define Hh 8
#define HD 16
#define BN 1024
#define G3 384   // 3*D

// workspace layout (in floats)
#define OFF_WX   0                              // 4*384
#define OFF_BX   1536                           // 384
#define OFF_U1   1920                           // 128*8
#define OFF_U2   2944                           // 128*8
#define OFF_YS   4096                           // T*BN*D
#define OFF_KK   (OFF_YS + Tt*BN*Dd)            // B*H*T*N*HD
#define OFF_QQ   (OFF_KK + Bb*Hh*Tt*Nn*HD)
#define OFF_VW1  (OFF_QQ + Bb*Hh*Tt*Nn*HD)      // B*H*T*N
#define OFF_VW2  (OFF_VW1 + Bb*Hh*Tt*Nn)
#define OFF_E    (OFF_VW2 + Bb*Hh*Tt*Nn)        // B*N*N
#define OFF_VV   (OFF_E + Bb*Nn*Nn)             // BN*D
#define WS_FLOATS (OFF_VV + BN*Dd)
// transient: f16x2-packed W_hh [64 pairs][384 cols] lives in KK region pre-k_kqv
#define OFF_WT   OFF_KK                         // 24576 u32 = 96 KB

typedef _Float16 half2_t __attribute__((ext_vector_type(2)));

__device__ __forceinline__ float fast_sigmoid(float v) {
  return 1.f / (1.f + __expf(-v));
}
__device__ __forceinline__ float fast_tanh(float v) {
  float e2 = __expf(2.f * v);
  return 1.f - 2.f / (e2 + 1.f);
}
__device__ __forceinline__ float fdot2(uint32_t a, uint32_t b, float c) {
  half2_t av = __builtin_bit_cast(half2_t, a);
  half2_t bv = __builtin_bit_cast(half2_t, b);
#if __has_builtin(__builtin_amdgcn_fdot2)
  return __builtin_amdgcn_fdot2(av, bv, c, false);
#else
  return c + (float)av.x * (float)bv.x + (float)av.y * (float)bv.y;
#endif
}

// ---------------- kernel 0: fold weights + pack W_hh to f16x2 ----------------
// block 0: fold W_se@W_ih, b fold, u1/u2; blocks 1..64: pack pair p = blk-1
__global__ __launch_bounds__(384) void k_precompute(
    const float* __restrict__ W_se, const float* __restrict__ b_se,
    const float* __restrict__ W_ih, const float* __restrict__ b_ih,
    const float* __restrict__ W_hh,
    const float* __restrict__ W_vc, const float* __restrict__ W_att,
    float* __restrict__ ws) {
  const int tid = threadIdx.x;
  if (blockIdx.x > 0) {
    const int p = blockIdx.x - 1;     // pair index 0..63
    uint32_t* WT = (uint32_t*)(ws + OFF_WT);
    if (tid < G3) {
      float w0 = W_hh[(size_t)(2*p)*G3 + tid];
      float w1 = W_hh[(size_t)(2*p+1)*G3 + tid];
      half2_t hv; hv.x = (_Float16)w0; hv.y = (_Float16)w1;
      WT[(size_t)p*G3 + tid] = __builtin_bit_cast(uint32_t, hv);
    }
    return;
  }
  const int c = tid; // 0..383
  float* Wx = ws + OFF_WX; float* bx = ws + OFF_BX;
  float* u1 = ws + OFF_U1; float* u2 = ws + OFF_U2;
  float accb = b_ih[c];
  float a0 = 0.f, a1 = 0.f, a2 = 0.f, a3 = 0.f;
  for (int k = 0; k < Dd; ++k) {
    float w = W_ih[k*G3 + c];
    accb = fmaf(b_se[k], w, accb);
    a0 = fmaf(W_se[0*Dd + k], w, a0);
    a1 = fmaf(W_se[1*Dd + k], w, a1);
    a2 = fmaf(W_se[2*Dd + k], w, a2);
    a3 = fmaf(W_se[3*Dd + k], w, a3);
  }
  bx[c] = accb;
  Wx[0*G3 + c] = a0; Wx[1*G3 + c] = a1; Wx[2*G3 + c] = a2; Wx[3*G3 + c] = a3;
  for (int idx = c; idx < Dd*Hh; idx += 384) {
    int k = idx >> 3, h = idx & 7;
    float s1 = 0.f, s2 = 0.f;
    for (int d = 0; d < HD; ++d) {
      float v = W_vc[k*Dd + h*HD + d];
      s1 = fmaf(v, W_att[h*HD + d], s1);
      s2 = fmaf(v, W_att[Dd + h*HD + d], s2);
    }
    u1[k*Hh + h] = s1;
    u2[k*Hh + h] = s2;
  }
}

// ---------------- kernel 1: GRU, W_hh f16x2 LDS-resident, v_dot2 ----------------
// 4 rows/block, 256 blocks (1 block/CU). W in dynamic LDS [64 pairs][384 cols]
// (conflict-free b32 per lane). h kept f32 in activation-thread registers,
// mirrored as f16 pairs in hp[4][64] for the dot phase.
__global__ __launch_bounds__(384) void k_gru(
    const float* __restrict__ x, const float* __restrict__ W_init,
    const float* __restrict__ b_init,
    const float* __restrict__ b_hh, float* __restrict__ ws) {
  extern __shared__ uint32_t WTl[];           // 24576 u32 = 96 KB
  __shared__ __align__(16) uint32_t hp[4][Dd/2];  // f16x2 h, 1 KB
  __shared__ float g_lds[4][4*Dd];            // [r|z|in|hn] per row, 8 KB
  __shared__ float xt_l[Tt+1][4][Ss];         // 4.1 KB
  const int tid = threadIdx.x;
  const int blk = blockIdx.x;
  const int row0 = blk * 4;
  const int b = row0 >> 6;
  const int n0 = row0 & 63;
  float* ys = ws + OFF_YS;
  const float* Wx = ws + OFF_WX;
  const float* bxp = ws + OFF_BX;
  const uint32_t* WTg = (const uint32_t*)(ws + OFF_WT);
  const int c = tid;

  // stage W into LDS: 24576 u32 via uint4 (coalesced)
  for (int i4 = tid; i4 < (64*G3)/4; i4 += 384)
    *(uint4*)&WTl[i4*4] = *(const uint4*)&WTg[i4*4];

  // stage x frames for our 4 rows: 65*4*4 = 1040 floats
  for (int idx = tid; idx < (Tt+1)*4*Ss; idx += 384) {
    int t = idx >> 4, r = (idx >> 2) & 3, s = idx & 3;
    xt_l[t][r][s] = x[((size_t)(b*(Tt+1) + t)*Nn + (n0 + r))*Ss + s];
  }
  __syncthreads();

  // h0 = x[:,0] @ W_init + b_init; activation thread (tid<256) owns rows
  // r2, r2+1 at dim d, keeps h in registers, mirrors f16 into hp.
  float hprev0 = 0.f, hprev1 = 0.f;
  int r2 = 0, dd = 0;
  if (tid < 2*Dd) {
    r2 = (tid >> 7) * 2; dd = tid & 127;
    float h0 = b_init[dd], h1 = b_init[dd];
    #pragma unroll
    for (int s = 0; s < Ss; ++s) {
      float wv = W_init[s*Dd + dd];
      h0 = fmaf(xt_l[0][r2+0][s], wv, h0);
      h1 = fmaf(xt_l[0][r2+1][s], wv, h1);
    }
    hprev0 = h0; hprev1 = h1;
    ((_Float16*)hp)[(r2+0)*Dd + dd] = (_Float16)h0;
    ((_Float16*)hp)[(r2+1)*Dd + dd] = (_Float16)h1;
  }
  const float bhh = b_hh[c];
  const float wx0 = Wx[0*G3 + c], wx1 = Wx[1*G3 + c], wx2 = Wx[2*G3 + c], wx3 = Wx[3*G3 + c];
  const float bxv = bxp[c];
  __syncthreads();

  for (int t = 0; t < Tt; ++t) {
    // gh[r][c] = b_hh[c] + h[r]·W_hh[:,c]  via f16x2 dot2
    float acc0 = bhh, acc1 = bhh, acc2 = bhh, acc3 = bhh;
    #pragma unroll
    for (int p4 = 0; p4 < 16; ++p4) {
      uint4 h0 = *(const uint4*)&hp[0][p4*4];
      uint4 h1 = *(const uint4*)&hp[1][p4*4];
      uint4 h2 = *(const uint4*)&hp[2][p4*4];
      uint4 h3 = *(const uint4*)&hp[3][p4*4];
      uint32_t w0 = WTl[(p4*4+0)*G3 + c];
      uint32_t w1 = WTl[(p4*4+1)*G3 + c];
      uint32_t w2 = WTl[(p4*4+2)*G3 + c];
      uint32_t w3 = WTl[(p4*4+3)*G3 + c];
      acc0 = fdot2(h0.x, w0, acc0); acc0 = fdot2(h0.y, w1, acc0);
      acc0 = fdot2(h0.z, w2, acc0); acc0 = fdot2(h0.w, w3, acc0);
      acc1 = fdot2(h1.x, w0, acc1); acc1 = fdot2(h1.y, w1, acc1);
      acc1 = fdot2(h1.z, w2, acc1); acc1 = fdot2(h1.w, w3, acc1);
      acc2 = fdot2(h2.x, w0, acc2); acc2 = fdot2(h2.y, w1, acc2);
      acc2 = fdot2(h2.z, w2, acc2); acc2 = fdot2(h2.w, w3, acc2);
      acc3 = fdot2(h3.x, w0, acc3); acc3 = fdot2(h3.y, w1, acc3);
      acc3 = fdot2(h3.z, w2, acc3); acc3 = fdot2(h3.w, w3, acc3);
    }
    float gi[4];
    #pragma unroll
    for (int r = 0; r < 4; ++r) {
      float g = bxv;
      g = fmaf(xt_l[t][r][0], wx0, g);
      g = fmaf(xt_l[t][r][1], wx1, g);
      g = fmaf(xt_l[t][r][2], wx2, g);
      g = fmaf(xt_l[t][r][3], wx3, g);
      gi[r] = g;
    }
    float accs[4] = {acc0, acc1, acc2, acc3};
    if (c < 2*Dd) {
      #pragma unroll
      for (int r = 0; r < 4; ++r) g_lds[r][c] = accs[r] + gi[r];
    } else {
      #pragma unroll
      for (int r = 0; r < 4; ++r) { g_lds[r][c] = gi[r]; g_lds[r][c + Dd] = accs[r]; }
    }
    __syncthreads();
    if (tid < 2*Dd) {
      // row r2
      {
        float rg = fast_sigmoid(g_lds[r2][dd]);
        float zg = fast_sigmoid(g_lds[r2][Dd + dd]);
        float ng = fast_tanh(fmaf(rg, g_lds[r2][3*Dd + dd], g_lds[r2][2*Dd + dd]));
        float hn = fmaf(zg, hprev0 - ng, ng);
        hprev0 = hn;
        ((_Float16*)hp)[r2*Dd + dd] = (_Float16)hn;
        ys[(size_t)(t*BN + row0 + r2)*Dd + dd] = hn;
      }
      // row r2+1
      {
        float rg = fast_sigmoid(g_lds[r2+1][dd]);
        float zg = fast_sigmoid(g_lds[r2+1][Dd + dd]);
        float ng = fast_tanh(fmaf(rg, g_lds[r2+1][3*Dd + dd], g_lds[r2+1][2*Dd + dd]));
        float hn = fmaf(zg, hprev1 - ng, ng);
        hprev1 = hn;
        ((_Float16*)hp)[(r2+1)*Dd + dd] = (_Float16)hn;
        ys[(size_t)(t*BN + row0 + r2 + 1)*Dd + dd] = hn;
      }
    }
    __syncthreads();
  }
}

// ---------------- kernel 2: k,q projections + vw scalars ----------------
__global__ __launch_bounds__(256) void k_kqv(
    const float* __restrict__ W_kc, const float* __restrict__ W_qc,
    float* __restrict__ ws) {
  __shared__ float ysl[64][Dd];  // 32KB
  const int tid = threadIdx.x;
  const int blk = blockIdx.x;    // b*T + t
  const int b = blk >> 6;
  const int t = blk & 63;
  const float* ysrc = ws + OFF_YS + (size_t)(t*BN + b*64)*Dd;
  for (int idx = tid; idx < 64*Dd; idx += 256) ((float*)ysl)[idx] = ysrc[idx];
  __syncthreads();

  const float* W = (tid < Dd) ? (W_kc + tid) : (W_qc + (tid - Dd));
  float acc[64];
  #pragma unroll
  for (int r = 0; r < 64; ++r) acc[r] = 0.f;
  for (int k = 0; k < Dd; k += 4) {
    float w0 = W[(k+0)*Dd];
    float w1 = W[(k+1)*Dd];
    float w2 = W[(k+2)*Dd];
    float w3 = W[(k+3)*Dd];
    #pragma unroll
    for (int r = 0; r < 64; ++r) {
      float4 hv = *(const float4*)&ysl[r][k];
      acc[r] = fmaf(hv.x, w0, acc[r]);
      acc[r] = fmaf(hv.y, w1, acc[r]);
      acc[r] = fmaf(hv.z, w2, acc[r]);
      acc[r] = fmaf(hv.w, w3, acc[r]);
    }
  }
  float* dst = ws + ((tid < Dd) ? OFF_KK : OFF_QQ);
  const int cc = tid & 127;
  const int h = cc >> 4, d = cc & 15;
  const size_t base = ((size_t)(b*Hh + h)*Tt + t)*(Nn*HD) + d;
  #pragma unroll
  for (int r = 0; r < 64; ++r) dst[base + (size_t)r*HD] = acc[r];

  const float* u1 = ws + OFF_U1;
  const float* u2 = ws + OFF_U2;
  for (int idx = tid; idx < 64*HD; idx += 256) {
    int r = idx >> 4, g = idx & 15, h2 = g >> 1, which = g & 1;
    const float* u = which ? u2 : u1;
    float s = 0.f;
    for (int k = 0; k < Dd; ++k) s = fmaf(ysl[r][k], u[k*Hh + h2], s);
    float* vw = ws + (which ? OFF_VW2 : OFF_VW1);
    vw[((size_t)(b*Hh + h2)*Tt + t)*Nn + r] = s;
  }
}

// ---------------- kernel 3: per-pair temporal online softmax -> e partials ----------------
__global__ __launch_bounds__(256) void k_attn(float* __restrict__ ws) {
  __shared__ float k_l[16*HD];
  __shared__ float q_l[HD*65];  // transposed, padded
  __shared__ float vw1_l[16], vw2_l[16];
  const int tid = threadIdx.x;
  const int blk = blockIdx.x;         // (b*H+h)*4 + quarter
  const int quarter = blk & 3;
  const int bh = blk >> 2;
  const int b = bh >> 3;
  const int i0 = quarter * 16;
  const float* kk = ws + OFF_KK + (size_t)bh*Tt*Nn*HD;
  const float* qq = ws + OFF_QQ + (size_t)bh*Tt*Nn*HD;
  const float* vw1 = ws + OFF_VW1 + (size_t)bh*Tt*Nn;
  const float* vw2 = ws + OFF_VW2 + (size_t)bh*Tt*Nn;
  float* e = ws + OFF_E + (size_t)b*Nn*Nn;
  const int j = tid & 63, wq = tid >> 6;
  float m[4], Ssum[4], A1[4], A2[4];
  #pragma unroll
  for (int p = 0; p < 4; ++p) { m[p] = -1e30f; Ssum[p] = 0.f; A1[p] = 0.f; A2[p] = 0.f; }
  const float scale = 0.08838834764831845f; // 1/sqrt(128)

  for (int t = 0; t < Tt; ++t) {
    __syncthreads();
    k_l[tid] = kk[(size_t)t*Nn*HD + i0*HD + tid];
    for (int idx = tid; idx < Nn*HD; idx += 256) {
      int jj = idx >> 4, d = idx & 15;
      q_l[d*65 + jj] = qq[(size_t)t*Nn*HD + idx];
    }
    if (tid < 16) vw1_l[tid] = vw1[(size_t)t*Nn + i0 + tid];
    else if (tid < 32) vw2_l[tid - 16] = vw2[(size_t)t*Nn + i0 + tid - 16];
    __syncthreads();
    float qr[16];
    #pragma unroll
    for (int d = 0; d < 16; ++d) qr[d] = q_l[d*65 + j];
    #pragma unroll
    for (int p = 0; p < 4; ++p) {
      const int il = wq + 4*p;
      float s = 0.f;
      #pragma unroll
      for (int d = 0; d < 16; ++d) s = fmaf(qr[d], k_l[il*HD + d], s);
      s *= scale;
      float mn = fmaxf(m[p], s);
      float cc = __expf(m[p] - mn);
      float pp = __expf(s - mn);
      Ssum[p] = fmaf(Ssum[p], cc, pp);
      A1[p] = fmaf(A1[p], cc, pp * vw1_l[il]);
      A2[p] = fmaf(A2[p], cc, pp * vw2_l[il]);
      m[p] = mn;
    }
  }
  #pragma unroll
  for (int p = 0; p < 4; ++p) {
    const int i = i0 + wq + 4*p;
    float inv = 1.f / Ssum[p];
    atomicAdd(&e[i*Nn + j], A1[p] * inv);
    atomicAdd(&e[j*Nn + i], A2[p] * inv);
  }
}

// ---------------- kernel 4: decode GRU step + vv ----------------
__global__ __launch_bounds__(384) void k_decode(
    const float* __restrict__ x, const float* __restrict__ W_hh,
    const float* __restrict__ b_hh, const float* __restrict__ W_val,
    const float* __restrict__ b_val, float* __restrict__ ws) {
  __shared__ float h_lds[4][Dd];
  __shared__ float g_lds[4][4*Dd];
  __shared__ float xt[4][Ss];
  const int tid = threadIdx.x;
  const int blk = blockIdx.x;
  const int row0 = blk * 4;
  const int b = row0 >> 6;
  const int n0 = row0 & 63;
  const float* ys = ws + OFF_YS;
  const float* Wx = ws + OFF_WX;
  const float* bxp = ws + OFF_BX;
  if (tid < Dd) {
    for (int r = 0; r < 4; ++r)
      h_lds[r][tid] = ys[(size_t)((Tt-1)*BN + row0 + r)*Dd + tid];
  }
  if (tid >= 320 && tid < 336) {
    int q = tid - 320; int r = q >> 2, s = q & 3;
    xt[r][s] = x[((size_t)(b*(Tt+1) + Tt)*Nn + (n0 + r))*Ss + s];
  }
  const int c = tid;
  const float bhh = b_hh[c];
  const float wx0 = Wx[0*G3 + c], wx1 = Wx[1*G3 + c], wx2 = Wx[2*G3 + c], wx3 = Wx[3*G3 + c];
  const float bxv = bxp[c];
  __syncthreads();
  float acc[4] = {bhh, bhh, bhh, bhh};
  for (int k = 0; k < Dd; k += 4) {
    float w0 = W_hh[(k+0)*G3 + c];
    float w1 = W_hh[(k+1)*G3 + c];
    float w2 = W_hh[(k+2)*G3 + c];
    float w3 = W_hh[(k+3)*G3 + c];
    #pragma unroll
    for (int r = 0; r < 4; ++r) {
      float4 hv = *(const float4*)&h_lds[r][k];
      acc[r] = fmaf(hv.x, w0, acc[r]);
      acc[r] = fmaf(hv.y, w1, acc[r]);
      acc[r] = fmaf(hv.z, w2, acc[r]);
      acc[r] = fmaf(hv.w, w3, acc[r]);
    }
  }
  float gi[4];
  #pragma unroll
  for (int r = 0; r < 4; ++r) {
    float g = bxv;
    g = fmaf(xt[r][0], wx0, g);
    g = fmaf(xt[r][1], wx1, g);
    g = fmaf(xt[r][2], wx2, g);
    g = fmaf(xt[r][3], wx3, g);
    gi[r] = g;
  }
  if (c < 2*Dd) {
    #pragma unroll
    for (int r = 0; r < 4; ++r) g_lds[r][c] = acc[r] + gi[r];
  } else {
    #pragma unroll
    for (int r = 0; r < 4; ++r) { g_lds[r][c] = gi[r]; g_lds[r][c + Dd] = acc[r]; }
  }
  __syncthreads();
  if (tid < Dd) {
    const int d = tid;
    #pragma unroll
    for (int r = 0; r < 4; ++r) {
      float rg = fast_sigmoid(g_lds[r][d]);
      float zg = fast_sigmoid(g_lds[r][Dd + d]);
      float ng = fast_tanh(fmaf(rg, g_lds[r][3*Dd + d], g_lds[r][2*Dd + d]));
      float hn = fmaf(zg, h_lds[r][d] - ng, ng);
      h_lds[r][d] = hn;
    }
  }
  __syncthreads();
  if (tid < Dd) {
    const int c2 = tid;
    for (int r = 0; r < 4; ++r) {
      float a = b_val[c2];
      for (int k = 0; k < Dd; k += 4) {
        float4 hv = *(const float4*)&h_lds[r][k];
        a = fmaf(hv.x, W_val[(k+0)*Dd + c2], a);
        a = fmaf(hv.y, W_val[(k+1)*Dd + c2], a);
        a = fmaf(hv.z, W_val[(k+2)*Dd + c2], a);
        a = fmaf(hv.w, W_val[(k+3)*Dd + c2], a);
      }
      ws[OFF_VV + (size_t)(row0 + r)*Dd + c2] = a;
    }
  }
}

// ---------------- kernel 5: weight/p/dec/mu/sig ----------------
__global__ __launch_bounds__(256) void k_final(
    const float* __restrict__ W_dec, const float* __restrict__ b_dec,
    const float* __restrict__ W_mu, const float* __restrict__ b_mu,
    const float* __restrict__ W_sig, const float* __restrict__ b_sig,
    const float* __restrict__ b_att, float* __restrict__ ws,
    float* __restrict__ out) {
  __shared__ float vvl[64][Dd];  // 32KB
  __shared__ float wl[16][64];
  __shared__ float pl[16][Dd];
  __shared__ float ddl[16][Dd];
  const int tid = threadIdx.x;
  const int blk = blockIdx.x;
  const int b = blk >> 2, iq = blk & 3, i0 = iq*16;
  const float* vv = ws + OFF_VV + (size_t)b*64*Dd;
  const float* e = ws + OFF_E + (size_t)b*Nn*Nn;
  const float batt = b_att[0];
  for (int idx = tid; idx < 64*Dd; idx += 256) ((float*)vvl)[idx] = vv[idx];
  for (int idx = tid; idx < 16*64; idx += 256) {
    int il = idx >> 6, jj = idx & 63;
    int i = i0 + il;
    wl[il][jj] = (i == jj) ? 0.f : fast_tanh(e[i*Nn + jj] + batt + 0.5f);
  }
  __syncthreads();
  {
    const int d = tid & 127, ih = tid >> 7;
    #pragma unroll
    for (int kk2 = 0; kk2 < 8; ++kk2) {
      int il = ih*8 + kk2;
      float a = 0.f;
      for (int jj = 0; jj < 64; ++jj) a = fmaf(wl[il][jj], vvl[jj][d], a);
      pl[il][d] = a * (1.f/64.f);
    }
  }
  __syncthreads();
  {
    const int e2 = tid & 127, ih = tid >> 7;
    #pragma unroll
    for (int kk2 = 0; kk2 < 8; ++kk2) {
      int il = ih*8 + kk2;
      float a = b_dec[e2];
      for (int c2 = 0; c2 < Dd; ++c2) a = fmaf(vvl[i0 + il][c2], W_dec[c2*Dd + e2], a);
      for (int c2 = 0; c2 < Dd; ++c2) a = fmaf(pl[il][c2], W_dec[(Dd + c2)*Dd + e2], a);
      ddl[il][e2] = a;
    }
  }
  __syncthreads();
  if (tid < 128) {
    const int il = tid >> 3, g = tid & 7, which = g >> 2, s = g & 3;
    const float* W = which ? W_sig : W_mu;
    float a = which ? b_sig[s] : b_mu[s];
    for (int k = 0; k < Dd; ++k) a = fmaf(ddl[il][k], W[k*Ss + s], a);
    if (which) a = 1.f/(1.f + __expf(-a)) + 1e-6f;
    out[(size_t)which*(Bb*Nn*Ss) + (size_t)(b*64 + i0 + il)*Ss + s] = a;
  }
}

extern "C" void kernel_launch(void* const* d_in, const int* in_sizes, int n_in,
                              void* d_out, int out_size, void* d_ws, size_t ws_size,
                              hipStream_t stream) {
  const float* x     = (const float*)d_in[0];
  const float* W_se  = (const float*)d_in[1];
  const float* b_se  = (const float*)d_in[2];
  const float* W_init= (const float*)d_in[3];
  const float* b_init= (const float*)d_in[4];
  const float* W_ih  = (const float*)d_in[5];
  const float* W_hh  = (const float*)d_in[6];
  const float* b_ih  = (const float*)d_in[7];
  const float* b_hh  = (const float*)d_in[8];
  const float* W_kc  = (const float*)d_in[9];
  const float* W_qc  = (const float*)d_in[10];
  const float* W_vc  = (const float*)d_in[11];
  const float* W_att = (const float*)d_in[12];
  const float* b_att = (const float*)d_in[13];
  const float* W_val = (const float*)d_in[14];
  const float* b_val = (const float*)d_in[15];
  const float* W_dec = (const float*)d_in[16];
  const float* b_dec = (const float*)d_in[17];
  const float* W_mu  = (const float*)d_in[18];
  const float* b_mu  = (const float*)d_in[19];
  const float* W_sig = (const float*)d_in[20];
  const float* b_sig = (const float*)d_in[21];
  float* ws = (float*)d_ws;
  float* out = (float*)d_out;

  if (ws_size < (size_t)WS_FLOATS * sizeof(float)) return;

  hipMemsetAsync(ws + OFF_E, 0, (size_t)Bb*Nn*Nn*sizeof(float), stream);
  k_precompute<<<65, 384, 0, stream>>>(W_se, b_se, W_ih, b_ih, W_hh, W_vc, W_att, ws);
  k_gru<<<BN/4, 384, 64*G3*sizeof(uint32_t), stream>>>(x, W_init, b_init, b_hh, ws);
  k_kqv<<<Bb*Tt, 256, 0, stream>>>(W_kc, W_qc, ws);
  k_attn<<<Bb*Hh*4, 256, 0, stream>>>(ws);
  k_decode<<<BN/4, 384, 0, stream>>>(x, W_hh, b_hh, W_val, b_val, ws);
  k_final<<<Bb*4, 256, 0, stream>>>(W_dec, b_dec, W_mu, b_mu, W_sig, b_sig, b_att, ws, out);
}

// Round 5
// 430.930 us; speedup vs baseline: 1.7680x; 1.2282x over previous
//
#include <hip/hip_runtime.h>
#include <math.h>

#define Bb 16
#define Tt 64
#define Nn 64
#define Ss 4
#define Dd 128
#define Hh 8
#define HD 16
#define BN 1024
#define G3 384   // 3*D
#define TT 8     // t-chunk for k_attn

// workspace layout (in floats)
#define OFF_WX   0                              // 4*384
#define OFF_BX   1536                           // 384
#define OFF_U1   1920                           // 128*8
#define OFF_U2   2944                           // 128*8
#define OFF_YS   4096                           // T*BN*D
#define OFF_KK   (OFF_YS + Tt*BN*Dd)            // B*H*T*N*HD
#define OFF_QQ   (OFF_KK + Bb*Hh*Tt*Nn*HD)
#define OFF_VW1  (OFF_QQ + Bb*Hh*Tt*Nn*HD)      // B*H*T*N
#define OFF_VW2  (OFF_VW1 + Bb*Hh*Tt*Nn)
#define OFF_E    (OFF_VW2 + Bb*Hh*Tt*Nn)        // B*N*N
#define OFF_VV   (OFF_E + Bb*Nn*Nn)             // BN*D
#define WS_FLOATS (OFF_VV + BN*Dd)
// transient: f16x2-packed W_hh [64 pairs][384 cols] lives in KK region pre-k_kqv
#define OFF_WT   OFF_KK                         // 24576 u32 = 96 KB

typedef _Float16 half2_t __attribute__((ext_vector_type(2)));

__device__ __forceinline__ float fast_sigmoid(float v) {
  return 1.f / (1.f + __expf(-v));
}
__device__ __forceinline__ float fast_tanh(float v) {
  float e2 = __expf(2.f * v);
  return 1.f - 2.f / (e2 + 1.f);
}
__device__ __forceinline__ float fdot2(uint32_t a, uint32_t b, float c) {
  half2_t av = __builtin_bit_cast(half2_t, a);
  half2_t bv = __builtin_bit_cast(half2_t, b);
#if __has_builtin(__builtin_amdgcn_fdot2)
  return __builtin_amdgcn_fdot2(av, bv, c, false);
#else
  return c + (float)av.x * (float)bv.x + (float)av.y * (float)bv.y;
#endif
}

// ---------------- kernel 0: fold weights + pack W_hh to f16x2 ----------------
__global__ __launch_bounds__(384) void k_precompute(
    const float* __restrict__ W_se, const float* __restrict__ b_se,
    const float* __restrict__ W_ih, const float* __restrict__ b_ih,
    const float* __restrict__ W_hh,
    const float* __restrict__ W_vc, const float* __restrict__ W_att,
    float* __restrict__ ws) {
  const int tid = threadIdx.x;
  if (blockIdx.x > 0) {
    const int p = blockIdx.x - 1;     // pair index 0..63
    uint32_t* WT = (uint32_t*)(ws + OFF_WT);
    if (tid < G3) {
      float w0 = W_hh[(size_t)(2*p)*G3 + tid];
      float w1 = W_hh[(size_t)(2*p+1)*G3 + tid];
      half2_t hv; hv.x = (_Float16)w0; hv.y = (_Float16)w1;
      WT[(size_t)p*G3 + tid] = __builtin_bit_cast(uint32_t, hv);
    }
    return;
  }
  const int c = tid; // 0..383
  float* Wx = ws + OFF_WX; float* bx = ws + OFF_BX;
  float* u1 = ws + OFF_U1; float* u2 = ws + OFF_U2;
  float accb = b_ih[c];
  float a0 = 0.f, a1 = 0.f, a2 = 0.f, a3 = 0.f;
  for (int k = 0; k < Dd; ++k) {
    float w = W_ih[k*G3 + c];
    accb = fmaf(b_se[k], w, accb);
    a0 = fmaf(W_se[0*Dd + k], w, a0);
    a1 = fmaf(W_se[1*Dd + k], w, a1);
    a2 = fmaf(W_se[2*Dd + k], w, a2);
    a3 = fmaf(W_se[3*Dd + k], w, a3);
  }
  bx[c] = accb;
  Wx[0*G3 + c] = a0; Wx[1*G3 + c] = a1; Wx[2*G3 + c] = a2; Wx[3*G3 + c] = a3;
  for (int idx = c; idx < Dd*Hh; idx += 384) {
    int k = idx >> 3, h = idx & 7;
    float s1 = 0.f, s2 = 0.f;
    for (int d = 0; d < HD; ++d) {
      float v = W_vc[k*Dd + h*HD + d];
      s1 = fmaf(v, W_att[h*HD + d], s1);
      s2 = fmaf(v, W_att[Dd + h*HD + d], s2);
    }
    u1[k*Hh + h] = s1;
    u2[k*Hh + h] = s2;
  }
}

// ---------------- kernel 1: GRU, W_hh f16x2 LDS-resident, v_dot2 ----------------
__global__ __launch_bounds__(384) void k_gru(
    const float* __restrict__ x, const float* __restrict__ W_init,
    const float* __restrict__ b_init,
    const float* __restrict__ b_hh, float* __restrict__ ws) {
  extern __shared__ uint32_t WTl[];           // 24576 u32 = 96 KB
  __shared__ __align__(16) uint32_t hp[4][Dd/2];  // f16x2 h, 1 KB
  __shared__ float g_lds[4][4*Dd];            // [r|z|in|hn] per row, 8 KB
  __shared__ float xt_l[Tt+1][4][Ss];         // 4.1 KB
  const int tid = threadIdx.x;
  const int blk = blockIdx.x;
  const int row0 = blk * 4;
  const int b = row0 >> 6;
  const int n0 = row0 & 63;
  float* ys = ws + OFF_YS;
  const float* Wx = ws + OFF_WX;
  const float* bxp = ws + OFF_BX;
  const uint32_t* WTg = (const uint32_t*)(ws + OFF_WT);
  const int c = tid;

  for (int i4 = tid; i4 < (64*G3)/4; i4 += 384)
    *(uint4*)&WTl[i4*4] = *(const uint4*)&WTg[i4*4];

  for (int idx = tid; idx < (Tt+1)*4*Ss; idx += 384) {
    int t = idx >> 4, r = (idx >> 2) & 3, s = idx & 3;
    xt_l[t][r][s] = x[((size_t)(b*(Tt+1) + t)*Nn + (n0 + r))*Ss + s];
  }
  __syncthreads();

  float hprev0 = 0.f, hprev1 = 0.f;
  int r2 = 0, dd = 0;
  if (tid < 2*Dd) {
    r2 = (tid >> 7) * 2; dd = tid & 127;
    float h0 = b_init[dd], h1 = b_init[dd];
    #pragma unroll
    for (int s = 0; s < Ss; ++s) {
      float wv = W_init[s*Dd + dd];
      h0 = fmaf(xt_l[0][r2+0][s], wv, h0);
      h1 = fmaf(xt_l[0][r2+1][s], wv, h1);
    }
    hprev0 = h0; hprev1 = h1;
    ((_Float16*)hp)[(r2+0)*Dd + dd] = (_Float16)h0;
    ((_Float16*)hp)[(r2+1)*Dd + dd] = (_Float16)h1;
  }
  const float bhh = b_hh[c];
  const float wx0 = Wx[0*G3 + c], wx1 = Wx[1*G3 + c], wx2 = Wx[2*G3 + c], wx3 = Wx[3*G3 + c];
  const float bxv = bxp[c];
  __syncthreads();

  for (int t = 0; t < Tt; ++t) {
    float acc0 = bhh, acc1 = bhh, acc2 = bhh, acc3 = bhh;
    #pragma unroll
    for (int p4 = 0; p4 < 16; ++p4) {
      uint4 h0 = *(const uint4*)&hp[0][p4*4];
      uint4 h1 = *(const uint4*)&hp[1][p4*4];
      uint4 h2 = *(const uint4*)&hp[2][p4*4];
      uint4 h3 = *(const uint4*)&hp[3][p4*4];
      uint32_t w0 = WTl[(p4*4+0)*G3 + c];
      uint32_t w1 = WTl[(p4*4+1)*G3 + c];
      uint32_t w2 = WTl[(p4*4+2)*G3 + c];
      uint32_t w3 = WTl[(p4*4+3)*G3 + c];
      acc0 = fdot2(h0.x, w0, acc0); acc0 = fdot2(h0.y, w1, acc0);
      acc0 = fdot2(h0.z, w2, acc0); acc0 = fdot2(h0.w, w3, acc0);
      acc1 = fdot2(h1.x, w0, acc1); acc1 = fdot2(h1.y, w1, acc1);
      acc1 = fdot2(h1.z, w2, acc1); acc1 = fdot2(h1.w, w3, acc1);
      acc2 = fdot2(h2.x, w0, acc2); acc2 = fdot2(h2.y, w1, acc2);
      acc2 = fdot2(h2.z, w2, acc2); acc2 = fdot2(h2.w, w3, acc2);
      acc3 = fdot2(h3.x, w0, acc3); acc3 = fdot2(h3.y, w1, acc3);
      acc3 = fdot2(h3.z, w2, acc3); acc3 = fdot2(h3.w, w3, acc3);
    }
    float gi[4];
    #pragma unroll
    for (int r = 0; r < 4; ++r) {
      float g = bxv;
      g = fmaf(xt_l[t][r][0], wx0, g);
      g = fmaf(xt_l[t][r][1], wx1, g);
      g = fmaf(xt_l[t][r][2], wx2, g);
      g = fmaf(xt_l[t][r][3], wx3, g);
      gi[r] = g;
    }
    float accs[4] = {acc0, acc1, acc2, acc3};
    if (c < 2*Dd) {
      #pragma unroll
      for (int r = 0; r < 4; ++r) g_lds[r][c] = accs[r] + gi[r];
    } else {
      #pragma unroll
      for (int r = 0; r < 4; ++r) { g_lds[r][c] = gi[r]; g_lds[r][c + Dd] = accs[r]; }
    }
    __syncthreads();
    if (tid < 2*Dd) {
      {
        float rg = fast_sigmoid(g_lds[r2][dd]);
        float zg = fast_sigmoid(g_lds[r2][Dd + dd]);
        float ng = fast_tanh(fmaf(rg, g_lds[r2][3*Dd + dd], g_lds[r2][2*Dd + dd]));
        float hn = fmaf(zg, hprev0 - ng, ng);
        hprev0 = hn;
        ((_Float16*)hp)[r2*Dd + dd] = (_Float16)hn;
        ys[(size_t)(t*BN + row0 + r2)*Dd + dd] = hn;
      }
      {
        float rg = fast_sigmoid(g_lds[r2+1][dd]);
        float zg = fast_sigmoid(g_lds[r2+1][Dd + dd]);
        float ng = fast_tanh(fmaf(rg, g_lds[r2+1][3*Dd + dd], g_lds[r2+1][2*Dd + dd]));
        float hn = fmaf(zg, hprev1 - ng, ng);
        hprev1 = hn;
        ((_Float16*)hp)[(r2+1)*Dd + dd] = (_Float16)hn;
        ys[(size_t)(t*BN + row0 + r2 + 1)*Dd + dd] = hn;
      }
    }
    __syncthreads();
  }
}

// ---------------- kernel 2: k,q projections + vw scalars ----------------
__global__ __launch_bounds__(256) void k_kqv(
    const float* __restrict__ W_kc, const float* __restrict__ W_qc,
    float* __restrict__ ws) {
  __shared__ float ysl[64][Dd];  // 32KB
  const int tid = threadIdx.x;
  const int blk = blockIdx.x;    // b*T + t
  const int b = blk >> 6;
  const int t = blk & 63;
  const float* ysrc = ws + OFF_YS + (size_t)(t*BN + b*64)*Dd;
  for (int idx = tid; idx < 64*Dd; idx += 256) ((float*)ysl)[idx] = ysrc[idx];
  __syncthreads();

  const float* W = (tid < Dd) ? (W_kc + tid) : (W_qc + (tid - Dd));
  float acc[64];
  #pragma unroll
  for (int r = 0; r < 64; ++r) acc[r] = 0.f;
  for (int k = 0; k < Dd; k += 4) {
    float w0 = W[(k+0)*Dd];
    float w1 = W[(k+1)*Dd];
    float w2 = W[(k+2)*Dd];
    float w3 = W[(k+3)*Dd];
    #pragma unroll
    for (int r = 0; r < 64; ++r) {
      float4 hv = *(const float4*)&ysl[r][k];
      acc[r] = fmaf(hv.x, w0, acc[r]);
      acc[r] = fmaf(hv.y, w1, acc[r]);
      acc[r] = fmaf(hv.z, w2, acc[r]);
      acc[r] = fmaf(hv.w, w3, acc[r]);
    }
  }
  float* dst = ws + ((tid < Dd) ? OFF_KK : OFF_QQ);
  const int cc = tid & 127;
  const int h = cc >> 4, d = cc & 15;
  const size_t base = ((size_t)(b*Hh + h)*Tt + t)*(Nn*HD) + d;
  #pragma unroll
  for (int r = 0; r < 64; ++r) dst[base + (size_t)r*HD] = acc[r];

  const float* u1 = ws + OFF_U1;
  const float* u2 = ws + OFF_U2;
  for (int idx = tid; idx < 64*HD; idx += 256) {
    int r = idx >> 4, g = idx & 15, h2 = g >> 1, which = g & 1;
    const float* u = which ? u2 : u1;
    float s = 0.f;
    for (int k = 0; k < Dd; ++k) s = fmaf(ysl[r][k], u[k*Hh + h2], s);
    float* vw = ws + (which ? OFF_VW2 : OFF_VW1);
    vw[((size_t)(b*Hh + h2)*Tt + t)*Nn + r] = s;
  }
}

// ---------------- kernel 3: per-pair temporal online softmax, t-chunked LDS ----------------
// block = (b,h,quarter); 256 threads (j=tid&63, wq=tid>>6); thread owns 4 i's.
// K-quarter chunk [16i][TT][16d] (broadcast b128 reads), Q chunk transposed
// [TT][16d][65j] (2-way b32 reads), vw chunks. 2 barriers per TT=8 steps.
__global__ __launch_bounds__(256) void k_attn(float* __restrict__ ws) {
  __shared__ __align__(16) float k_l[16][TT][HD];   // 8 KB
  __shared__ float q_l[TT][HD][Nn+1];               // 33.3 KB
  __shared__ float vw1_l[TT][16], vw2_l[TT][16];    // 1 KB
  const int tid = threadIdx.x;
  const int blk = blockIdx.x;         // (b*H+h)*4 + quarter
  const int quarter = blk & 3;
  const int bh = blk >> 2;
  const int b = bh >> 3;
  const int i0 = quarter * 16;
  const float* kk = ws + OFF_KK + (size_t)bh*Tt*Nn*HD;
  const float* qq = ws + OFF_QQ + (size_t)bh*Tt*Nn*HD;
  const float* vw1 = ws + OFF_VW1 + (size_t)bh*Tt*Nn;
  const float* vw2 = ws + OFF_VW2 + (size_t)bh*Tt*Nn;
  float* e = ws + OFF_E + (size_t)b*Nn*Nn;
  const int j = tid & 63, wq = tid >> 6;
  float m[4], Ssum[4], A1[4], A2[4];
  #pragma unroll
  for (int p = 0; p < 4; ++p) { m[p] = -1e30f; Ssum[p] = 0.f; A1[p] = 0.f; A2[p] = 0.f; }
  const float scale = 0.08838834764831845f; // 1/sqrt(128)

  for (int tc = 0; tc < Tt/TT; ++tc) {
    const int tbase = tc * TT;
    __syncthreads();   // protect LDS from previous chunk's readers
    // stage K: 16i*TT*16d = 2048 floats = 512 float4; 2 per thread
    #pragma unroll
    for (int s = 0; s < 2; ++s) {
      int fi = tid + s*256;
      int d4 = fi & 3, ttl = (fi >> 2) & 7, il = fi >> 5;
      float4 v = *(const float4*)&kk[((size_t)(tbase + ttl)*Nn + i0 + il)*HD + d4*4];
      *(float4*)&k_l[il][ttl][d4*4] = v;
    }
    // stage Q transposed: TT*64*16 = 8192 floats = 2048 float4; 8 per thread
    #pragma unroll
    for (int s = 0; s < 8; ++s) {
      int fi = tid + s*256;
      int d4 = fi & 3, jg = (fi >> 2) & 63, ttl = fi >> 8;
      float4 v = *(const float4*)&qq[((size_t)(tbase + ttl)*Nn + jg)*HD + d4*4];
      q_l[ttl][d4*4+0][jg] = v.x;
      q_l[ttl][d4*4+1][jg] = v.y;
      q_l[ttl][d4*4+2][jg] = v.z;
      q_l[ttl][d4*4+3][jg] = v.w;
    }
    // stage vw: 2*TT*16 = 256
    {
      int which = tid >> 7, ttl = (tid >> 4) & 7, ii = tid & 15;
      const float* src = which ? vw2 : vw1;
      float v = src[(size_t)(tbase + ttl)*Nn + i0 + ii];
      if (which) vw2_l[ttl][ii] = v; else vw1_l[ttl][ii] = v;
    }
    __syncthreads();

    for (int ttl = 0; ttl < TT; ++ttl) {
      float qr[16];
      #pragma unroll
      for (int d = 0; d < 16; ++d) qr[d] = q_l[ttl][d][j];
      #pragma unroll
      for (int p = 0; p < 4; ++p) {
        const int il = wq + 4*p;
        float4 k0 = *(const float4*)&k_l[il][ttl][0];
        float4 k1 = *(const float4*)&k_l[il][ttl][4];
        float4 k2 = *(const float4*)&k_l[il][ttl][8];
        float4 k3 = *(const float4*)&k_l[il][ttl][12];
        float s = 0.f;
        s = fmaf(qr[0],  k0.x, s); s = fmaf(qr[1],  k0.y, s);
        s = fmaf(qr[2],  k0.z, s); s = fmaf(qr[3],  k0.w, s);
        s = fmaf(qr[4],  k1.x, s); s = fmaf(qr[5],  k1.y, s);
        s = fmaf(qr[6],  k1.z, s); s = fmaf(qr[7],  k1.w, s);
        s = fmaf(qr[8],  k2.x, s); s = fmaf(qr[9],  k2.y, s);
        s = fmaf(qr[10], k2.z, s); s = fmaf(qr[11], k2.w, s);
        s = fmaf(qr[12], k3.x, s); s = fmaf(qr[13], k3.y, s);
        s = fmaf(qr[14], k3.z, s); s = fmaf(qr[15], k3.w, s);
        s *= scale;
        float mn = fmaxf(m[p], s);
        float cc2 = __expf(m[p] - mn);
        float pp = __expf(s - mn);
        Ssum[p] = fmaf(Ssum[p], cc2, pp);
        A1[p] = fmaf(A1[p], cc2, pp * vw1_l[ttl][il]);
        A2[p] = fmaf(A2[p], cc2, pp * vw2_l[ttl][il]);
        m[p] = mn;
      }
    }
  }
  #pragma unroll
  for (int p = 0; p < 4; ++p) {
    const int i = i0 + wq + 4*p;
    float inv = 1.f / Ssum[p];
    atomicAdd(&e[i*Nn + j], A1[p] * inv);
    atomicAdd(&e[j*Nn + i], A2[p] * inv);
  }
}

// ---------------- kernel 4: decode GRU step + vv ----------------
__global__ __launch_bounds__(384) void k_decode(
    const float* __restrict__ x, const float* __restrict__ W_hh,
    const float* __restrict__ b_hh, const float* __restrict__ W_val,
    const float* __restrict__ b_val, float* __restrict__ ws) {
  __shared__ float h_lds[4][Dd];
  __shared__ float g_lds[4][4*Dd];
  __shared__ float xt[4][Ss];
  const int tid = threadIdx.x;
  const int blk = blockIdx.x;
  const int row0 = blk * 4;
  const int b = row0 >> 6;
  const int n0 = row0 & 63;
  const float* ys = ws + OFF_YS;
  const float* Wx = ws + OFF_WX;
  const float* bxp = ws + OFF_BX;
  if (tid < Dd) {
    for (int r = 0; r < 4; ++r)
      h_lds[r][tid] = ys[(size_t)((Tt-1)*BN + row0 + r)*Dd + tid];
  }
  if (tid >= 320 && tid < 336) {
    int q = tid - 320; int r = q >> 2, s = q & 3;
    xt[r][s] = x[((size_t)(b*(Tt+1) + Tt)*Nn + (n0 + r))*Ss + s];
  }
  const int c = tid;
  const float bhh = b_hh[c];
  const float wx0 = Wx[0*G3 + c], wx1 = Wx[1*G3 + c], wx2 = Wx[2*G3 + c], wx3 = Wx[3*G3 + c];
  const float bxv = bxp[c];
  __syncthreads();
  float acc[4] = {bhh, bhh, bhh, bhh};
  for (int k = 0; k < Dd; k += 4) {
    float w0 = W_hh[(k+0)*G3 + c];
    float w1 = W_hh[(k+1)*G3 + c];
    float w2 = W_hh[(k+2)*G3 + c];
    float w3 = W_hh[(k+3)*G3 + c];
    #pragma unroll
    for (int r = 0; r < 4; ++r) {
      float4 hv = *(const float4*)&h_lds[r][k];
      acc[r] = fmaf(hv.x, w0, acc[r]);
      acc[r] = fmaf(hv.y, w1, acc[r]);
      acc[r] = fmaf(hv.z, w2, acc[r]);
      acc[r] = fmaf(hv.w, w3, acc[r]);
    }
  }
  float gi[4];
  #pragma unroll
  for (int r = 0; r < 4; ++r) {
    float g = bxv;
    g = fmaf(xt[r][0], wx0, g);
    g = fmaf(xt[r][1], wx1, g);
    g = fmaf(xt[r][2], wx2, g);
    g = fmaf(xt[r][3], wx3, g);
    gi[r] = g;
  }
  if (c < 2*Dd) {
    #pragma unroll
    for (int r = 0; r < 4; ++r) g_lds[r][c] = acc[r] + gi[r];
  } else {
    #pragma unroll
    for (int r = 0; r < 4; ++r) { g_lds[r][c] = gi[r]; g_lds[r][c + Dd] = acc[r]; }
  }
  __syncthreads();
  if (tid < Dd) {
    const int d = tid;
    #pragma unroll
    for (int r = 0; r < 4; ++r) {
      float rg = fast_sigmoid(g_lds[r][d]);
      float zg = fast_sigmoid(g_lds[r][Dd + d]);
      float ng = fast_tanh(fmaf(rg, g_lds[r][3*Dd + d], g_lds[r][2*Dd + d]));
      float hn = fmaf(zg, h_lds[r][d] - ng, ng);
      h_lds[r][d] = hn;
    }
  }
  __syncthreads();
  if (tid < Dd) {
    const int c2 = tid;
    for (int r = 0; r < 4; ++r) {
      float a = b_val[c2];
      for (int k = 0; k < Dd; k += 4) {
        float4 hv = *(const float4*)&h_lds[r][k];
        a = fmaf(hv.x, W_val[(k+0)*Dd + c2], a);
        a = fmaf(hv.y, W_val[(k+1)*Dd + c2], a);
        a = fmaf(hv.z, W_val[(k+2)*Dd + c2], a);
        a = fmaf(hv.w, W_val[(k+3)*Dd + c2], a);
      }
      ws[OFF_VV + (size_t)(row0 + r)*Dd + c2] = a;
    }
  }
}

// ---------------- kernel 5: weight/p/dec/mu/sig ----------------
__global__ __launch_bounds__(256) void k_final(
    const float* __restrict__ W_dec, const float* __restrict__ b_dec,
    const float* __restrict__ W_mu, const float* __restrict__ b_mu,
    const float* __restrict__ W_sig, const float* __restrict__ b_sig,
    const float* __restrict__ b_att, float* __restrict__ ws,
    float* __restrict__ out) {
  __shared__ float vvl[64][Dd];  // 32KB
  __shared__ float wl[16][64];
  __shared__ float pl[16][Dd];
  __shared__ float ddl[16][Dd];
  const int tid = threadIdx.x;
  const int blk = blockIdx.x;
  const int b = blk >> 2, iq = blk & 3, i0 = iq*16;
  const float* vv = ws + OFF_VV + (size_t)b*64*Dd;
  const float* e = ws + OFF_E + (size_t)b*Nn*Nn;
  const float batt = b_att[0];
  for (int idx = tid; idx < 64*Dd; idx += 256) ((float*)vvl)[idx] = vv[idx];
  for (int idx = tid; idx < 16*64; idx += 256) {
    int il = idx >> 6, jj = idx & 63;
    int i = i0 + il;
    wl[il][jj] = (i == jj) ? 0.f : fast_tanh(e[i*Nn + jj] + batt + 0.5f);
  }
  __syncthreads();
  {
    const int d = tid & 127, ih = tid >> 7;
    #pragma unroll
    for (int kk2 = 0; kk2 < 8; ++kk2) {
      int il = ih*8 + kk2;
      float a = 0.f;
      for (int jj = 0; jj < 64; ++jj) a = fmaf(wl[il][jj], vvl[jj][d], a);
      pl[il][d] = a * (1.f/64.f);
    }
  }
  __syncthreads();
  {
    const int e2 = tid & 127, ih = tid >> 7;
    #pragma unroll
    for (int kk2 = 0; kk2 < 8; ++kk2) {
      int il = ih*8 + kk2;
      float a = b_dec[e2];
      for (int c2 = 0; c2 < Dd; ++c2) a = fmaf(vvl[i0 + il][c2], W_dec[c2*Dd + e2], a);
      for (int c2 = 0; c2 < Dd; ++c2) a = fmaf(pl[il][c2], W_dec[(Dd + c2)*Dd + e2], a);
      ddl[il][e2] = a;
    }
  }
  __syncthreads();
  if (tid < 128) {
    const int il = tid >> 3, g = tid & 7, which = g >> 2, s = g & 3;
    const float* W = which ? W_sig : W_mu;
    float a = which ? b_sig[s] : b_mu[s];
    for (int k = 0; k < Dd; ++k) a = fmaf(ddl[il][k], W[k*Ss + s], a);
    if (which) a = 1.f/(1.f + __expf(-a)) + 1e-6f;
    out[(size_t)which*(Bb*Nn*Ss) + (size_t)(b*64 + i0 + il)*Ss + s] = a;
  }
}

extern "C" void kernel_launch(void* const* d_in, const int* in_sizes, int n_in,
                              void* d_out, int out_size, void* d_ws, size_t ws_size,
                              hipStream_t stream) {
  const float* x     = (const float*)d_in[0];
  const float* W_se  = (const float*)d_in[1];
  const float* b_se  = (const float*)d_in[2];
  const float* W_init= (const float*)d_in[3];
  const float* b_init= (const float*)d_in[4];
  const float* W_ih  = (const float*)d_in[5];
  const float* W_hh  = (const float*)d_in[6];
  const float* b_ih  = (const float*)d_in[7];
  const float* b_hh  = (const float*)d_in[8];
  const float* W_kc  = (const float*)d_in[9];
  const float* W_qc  = (const float*)d_in[10];
  const float* W_vc  = (const float*)d_in[11];
  const float* W_att = (const float*)d_in[12];
  const float* b_att = (const float*)d_in[13];
  const float* W_val = (const float*)d_in[14];
  const float* b_val = (const float*)d_in[15];
  const float* W_dec = (const float*)d_in[16];
  const float* b_dec = (const float*)d_in[17];
  const float* W_mu  = (const float*)d_in[18];
  const float* b_mu  = (const float*)d_in[19];
  const float* W_sig = (const float*)d_in[20];
  const float* b_sig = (const float*)d_in[21];
  float* ws = (float*)d_ws;
  float* out = (float*)d_out;

  if (ws_size < (size_t)WS_FLOATS * sizeof(float)) return;

  hipMemsetAsync(ws + OFF_E, 0, (size_t)Bb*Nn*Nn*sizeof(float), stream);
  k_precompute<<<65, 384, 0, stream>>>(W_se, b_se, W_ih, b_ih, W_hh, W_vc, W_att, ws);
  k_gru<<<BN/4, 384, 64*G3*sizeof(uint32_t), stream>>>(x, W_init, b_init, b_hh, ws);
  k_kqv<<<Bb*Tt, 256, 0, stream>>>(W_kc, W_qc, ws);
  k_attn<<<Bb*Hh*4, 256, 0, stream>>>(ws);
  k_decode<<<BN/4, 384, 0, stream>>>(x, W_hh, b_hh, W_val, b_val, ws);
  k_final<<<Bb*4, 256, 0, stream>>>(W_dec, b_dec, W_mu, b_mu, W_sig, b_sig, b_att, ws, out);
}

// Round 6
// 410.686 us; speedup vs baseline: 1.8551x; 1.0493x over previous
//
#include <hip/hip_runtime.h>
#include <math.h>

#define Bb 16
#define Tt 64
#define Nn 64
#define Ss 4
#define Dd 128
#define Hh 8
#define HD 16
#define BN 1024
#define G3 384   // 3*D
#define TT 8     // t-chunk for k_attn

// workspace layout (in floats)
#define OFF_WX   0                              // 4*384
#define OFF_BX   1536                           // 384
#define OFF_U1   1920                           // 128*8
#define OFF_U2   2944                           // 128*8
#define OFF_YS   4096                           // T*BN*D
#define OFF_KK   (OFF_YS + Tt*BN*Dd)            // [(b*T+t)*N + n]*D  (c = h*16+d)
#define OFF_QQ   (OFF_KK + Bb*Tt*Nn*Dd)
#define OFF_VW1  (OFF_QQ + Bb*Tt*Nn*Dd)         // [b][h][t][n]
#define OFF_VW2  (OFF_VW1 + Bb*Hh*Tt*Nn)
#define OFF_E    (OFF_VW2 + Bb*Hh*Tt*Nn)        // B*N*N
#define OFF_VV   (OFF_E + Bb*Nn*Nn)             // BN*D
#define WS_FLOATS (OFF_VV + BN*Dd)
// transient: f16x2-packed W_hh [64 pairs][384 cols] lives in KK region pre-k_kqv
#define OFF_WT   OFF_KK                         // 24576 u32 = 96 KB

typedef _Float16 half2_t __attribute__((ext_vector_type(2)));

__device__ __forceinline__ float fast_sigmoid(float v) {
  return 1.f / (1.f + __expf(-v));
}
__device__ __forceinline__ float fast_tanh(float v) {
  float e2 = __expf(2.f * v);
  return 1.f - 2.f / (e2 + 1.f);
}
__device__ __forceinline__ float fdot2(uint32_t a, uint32_t b, float c) {
  half2_t av = __builtin_bit_cast(half2_t, a);
  half2_t bv = __builtin_bit_cast(half2_t, b);
#if __has_builtin(__builtin_amdgcn_fdot2)
  return __builtin_amdgcn_fdot2(av, bv, c, false);
#else
  return c + (float)av.x * (float)bv.x + (float)av.y * (float)bv.y;
#endif
}

// ---------------- kernel 0: fold weights + pack W_hh to f16x2 ----------------
__global__ __launch_bounds__(384) void k_precompute(
    const float* __restrict__ W_se, const float* __restrict__ b_se,
    const float* __restrict__ W_ih, const float* __restrict__ b_ih,
    const float* __restrict__ W_hh,
    const float* __restrict__ W_vc, const float* __restrict__ W_att,
    float* __restrict__ ws) {
  const int tid = threadIdx.x;
  if (blockIdx.x > 0) {
    const int p = blockIdx.x - 1;     // pair index 0..63
    uint32_t* WT = (uint32_t*)(ws + OFF_WT);
    if (tid < G3) {
      float w0 = W_hh[(size_t)(2*p)*G3 + tid];
      float w1 = W_hh[(size_t)(2*p+1)*G3 + tid];
      half2_t hv; hv.x = (_Float16)w0; hv.y = (_Float16)w1;
      WT[(size_t)p*G3 + tid] = __builtin_bit_cast(uint32_t, hv);
    }
    return;
  }
  const int c = tid; // 0..383
  float* Wx = ws + OFF_WX; float* bx = ws + OFF_BX;
  float* u1 = ws + OFF_U1; float* u2 = ws + OFF_U2;
  float accb = b_ih[c];
  float a0 = 0.f, a1 = 0.f, a2 = 0.f, a3 = 0.f;
  for (int k = 0; k < Dd; ++k) {
    float w = W_ih[k*G3 + c];
    accb = fmaf(b_se[k], w, accb);
    a0 = fmaf(W_se[0*Dd + k], w, a0);
    a1 = fmaf(W_se[1*Dd + k], w, a1);
    a2 = fmaf(W_se[2*Dd + k], w, a2);
    a3 = fmaf(W_se[3*Dd + k], w, a3);
  }
  bx[c] = accb;
  Wx[0*G3 + c] = a0; Wx[1*G3 + c] = a1; Wx[2*G3 + c] = a2; Wx[3*G3 + c] = a3;
  for (int idx = c; idx < Dd*Hh; idx += 384) {
    int k = idx >> 3, h = idx & 7;
    float s1 = 0.f, s2 = 0.f;
    for (int d = 0; d < HD; ++d) {
      float v = W_vc[k*Dd + h*HD + d];
      s1 = fmaf(v, W_att[h*HD + d], s1);
      s2 = fmaf(v, W_att[Dd + h*HD + d], s2);
    }
    u1[k*Hh + h] = s1;
    u2[k*Hh + h] = s2;
  }
}

// ---------------- kernel 1: GRU, W_hh f16x2 LDS-resident, v_dot2 ----------------
__global__ __launch_bounds__(384) void k_gru(
    const float* __restrict__ x, const float* __restrict__ W_init,
    const float* __restrict__ b_init,
    const float* __restrict__ b_hh, float* __restrict__ ws) {
  extern __shared__ uint32_t WTl[];           // 24576 u32 = 96 KB
  __shared__ __align__(16) uint32_t hp[4][Dd/2];  // f16x2 h, 1 KB
  __shared__ float g_lds[4][4*Dd];            // [r|z|in|hn] per row, 8 KB
  __shared__ float xt_l[Tt+1][4][Ss];         // 4.1 KB
  const int tid = threadIdx.x;
  const int blk = blockIdx.x;
  const int row0 = blk * 4;
  const int b = row0 >> 6;
  const int n0 = row0 & 63;
  float* ys = ws + OFF_YS;
  const float* Wx = ws + OFF_WX;
  const float* bxp = ws + OFF_BX;
  const uint32_t* WTg = (const uint32_t*)(ws + OFF_WT);
  const int c = tid;

  for (int i4 = tid; i4 < (64*G3)/4; i4 += 384)
    *(uint4*)&WTl[i4*4] = *(const uint4*)&WTg[i4*4];

  for (int idx = tid; idx < (Tt+1)*4*Ss; idx += 384) {
    int t = idx >> 4, r = (idx >> 2) & 3, s = idx & 3;
    xt_l[t][r][s] = x[((size_t)(b*(Tt+1) + t)*Nn + (n0 + r))*Ss + s];
  }
  __syncthreads();

  float hprev0 = 0.f, hprev1 = 0.f;
  int r2 = 0, dd = 0;
  if (tid < 2*Dd) {
    r2 = (tid >> 7) * 2; dd = tid & 127;
    float h0 = b_init[dd], h1 = b_init[dd];
    #pragma unroll
    for (int s = 0; s < Ss; ++s) {
      float wv = W_init[s*Dd + dd];
      h0 = fmaf(xt_l[0][r2+0][s], wv, h0);
      h1 = fmaf(xt_l[0][r2+1][s], wv, h1);
    }
    hprev0 = h0; hprev1 = h1;
    ((_Float16*)hp)[(r2+0)*Dd + dd] = (_Float16)h0;
    ((_Float16*)hp)[(r2+1)*Dd + dd] = (_Float16)h1;
  }
  const float bhh = b_hh[c];
  const float wx0 = Wx[0*G3 + c], wx1 = Wx[1*G3 + c], wx2 = Wx[2*G3 + c], wx3 = Wx[3*G3 + c];
  const float bxv = bxp[c];
  __syncthreads();

  for (int t = 0; t < Tt; ++t) {
    float acc0 = bhh, acc1 = bhh, acc2 = bhh, acc3 = bhh;
    #pragma unroll
    for (int p4 = 0; p4 < 16; ++p4) {
      uint4 h0 = *(const uint4*)&hp[0][p4*4];
      uint4 h1 = *(const uint4*)&hp[1][p4*4];
      uint4 h2 = *(const uint4*)&hp[2][p4*4];
      uint4 h3 = *(const uint4*)&hp[3][p4*4];
      uint32_t w0 = WTl[(p4*4+0)*G3 + c];
      uint32_t w1 = WTl[(p4*4+1)*G3 + c];
      uint32_t w2 = WTl[(p4*4+2)*G3 + c];
      uint32_t w3 = WTl[(p4*4+3)*G3 + c];
      acc0 = fdot2(h0.x, w0, acc0); acc0 = fdot2(h0.y, w1, acc0);
      acc0 = fdot2(h0.z, w2, acc0); acc0 = fdot2(h0.w, w3, acc0);
      acc1 = fdot2(h1.x, w0, acc1); acc1 = fdot2(h1.y, w1, acc1);
      acc1 = fdot2(h1.z, w2, acc1); acc1 = fdot2(h1.w, w3, acc1);
      acc2 = fdot2(h2.x, w0, acc2); acc2 = fdot2(h2.y, w1, acc2);
      acc2 = fdot2(h2.z, w2, acc2); acc2 = fdot2(h2.w, w3, acc2);
      acc3 = fdot2(h3.x, w0, acc3); acc3 = fdot2(h3.y, w1, acc3);
      acc3 = fdot2(h3.z, w2, acc3); acc3 = fdot2(h3.w, w3, acc3);
    }
    float gi[4];
    #pragma unroll
    for (int r = 0; r < 4; ++r) {
      float g = bxv;
      g = fmaf(xt_l[t][r][0], wx0, g);
      g = fmaf(xt_l[t][r][1], wx1, g);
      g = fmaf(xt_l[t][r][2], wx2, g);
      g = fmaf(xt_l[t][r][3], wx3, g);
      gi[r] = g;
    }
    float accs[4] = {acc0, acc1, acc2, acc3};
    if (c < 2*Dd) {
      #pragma unroll
      for (int r = 0; r < 4; ++r) g_lds[r][c] = accs[r] + gi[r];
    } else {
      #pragma unroll
      for (int r = 0; r < 4; ++r) { g_lds[r][c] = gi[r]; g_lds[r][c + Dd] = accs[r]; }
    }
    __syncthreads();
    if (tid < 2*Dd) {
      {
        float rg = fast_sigmoid(g_lds[r2][dd]);
        float zg = fast_sigmoid(g_lds[r2][Dd + dd]);
        float ng = fast_tanh(fmaf(rg, g_lds[r2][3*Dd + dd], g_lds[r2][2*Dd + dd]));
        float hn = fmaf(zg, hprev0 - ng, ng);
        hprev0 = hn;
        ((_Float16*)hp)[r2*Dd + dd] = (_Float16)hn;
        ys[(size_t)(t*BN + row0 + r2)*Dd + dd] = hn;
      }
      {
        float rg = fast_sigmoid(g_lds[r2+1][dd]);
        float zg = fast_sigmoid(g_lds[r2+1][Dd + dd]);
        float ng = fast_tanh(fmaf(rg, g_lds[r2+1][3*Dd + dd], g_lds[r2+1][2*Dd + dd]));
        float hn = fmaf(zg, hprev1 - ng, ng);
        hprev1 = hn;
        ((_Float16*)hp)[(r2+1)*Dd + dd] = (_Float16)hn;
        ys[(size_t)(t*BN + row0 + r2 + 1)*Dd + dd] = hn;
      }
    }
    __syncthreads();
  }
}

// ---------------- kernel 2: k,q projections, 8x8 register-tile GEMM ----------------
// block = (b,t): 64 rows x 256 cols (K||Q). 256 threads = 8x32 grid, 8x8 tile each.
// ys staged transposed in LDS; W read from L2 with 1-iter prefetch.
// K/Q written coalesced to layout [(b*T+t)*N + n]*128 + (h*16+d).
__global__ __launch_bounds__(256) void k_kqv(
    const float* __restrict__ W_kc, const float* __restrict__ W_qc,
    float* __restrict__ ws) {
  __shared__ __align__(16) float yslT[Dd][68];  // transposed, padded: 34.8 KB
  const int tid = threadIdx.x;
  const int blk = blockIdx.x;    // b*T + t
  const int b = blk >> 6;
  const int t = blk & 63;
  const float* ysrc = ws + OFF_YS + ((size_t)t*BN + b*64)*Dd;
  // stage transposed
  for (int idx = tid; idx < 64*Dd/4; idx += 256) {
    int r = idx >> 5, k4 = idx & 31;
    float4 v = *(const float4*)&ysrc[r*Dd + k4*4];
    yslT[k4*4+0][r] = v.x;
    yslT[k4*4+1][r] = v.y;
    yslT[k4*4+2][r] = v.z;
    yslT[k4*4+3][r] = v.w;
  }
  __syncthreads();

  const int rg = tid >> 5;          // 0..7  (row group)
  const int cg = tid & 31;          // 0..31 (col group)
  const int row0 = rg * 8;
  const float* Wm = (cg < 16) ? W_kc : W_qc;
  const int col0 = (cg & 15) * 8;
  const float* wp = Wm + col0;

  float acc[8][8];
  #pragma unroll
  for (int r = 0; r < 8; ++r)
    #pragma unroll
    for (int cc = 0; cc < 8; ++cc) acc[r][cc] = 0.f;

  float4 bv0 = *(const float4*)&wp[0];
  float4 bv1 = *(const float4*)&wp[4];
  for (int k = 0; k < Dd; ++k) {
    const int kn = (k + 1) & 127;
    float4 nb0 = *(const float4*)&wp[kn*Dd];
    float4 nb1 = *(const float4*)&wp[kn*Dd + 4];
    float4 a0 = *(const float4*)&yslT[k][row0];
    float4 a1 = *(const float4*)&yslT[k][row0 + 4];
    float ar[8] = {a0.x, a0.y, a0.z, a0.w, a1.x, a1.y, a1.z, a1.w};
    float br[8] = {bv0.x, bv0.y, bv0.z, bv0.w, bv1.x, bv1.y, bv1.z, bv1.w};
    #pragma unroll
    for (int r = 0; r < 8; ++r)
      #pragma unroll
      for (int cc = 0; cc < 8; ++cc)
        acc[r][cc] = fmaf(ar[r], br[cc], acc[r][cc]);
    bv0 = nb0; bv1 = nb1;
  }

  // coalesced writes
  float* dst = ws + ((cg < 16) ? OFF_KK : OFF_QQ);
  const size_t base = (size_t)blk * Nn * Dd;
  #pragma unroll
  for (int r = 0; r < 8; ++r) {
    float4 o0 = {acc[r][0], acc[r][1], acc[r][2], acc[r][3]};
    float4 o1 = {acc[r][4], acc[r][5], acc[r][6], acc[r][7]};
    *(float4*)&dst[base + (size_t)(row0 + r)*Dd + col0] = o0;
    *(float4*)&dst[base + (size_t)(row0 + r)*Dd + col0 + 4] = o1;
  }

  // vw1/vw2: [b][h][t][n]
  const float* u1 = ws + OFF_U1;
  const float* u2 = ws + OFF_U2;
  for (int idx = tid; idx < 64*HD; idx += 256) {
    int r = idx >> 4, g = idx & 15, h2 = g >> 1, which = g & 1;
    const float* u = which ? u2 : u1;
    float s = 0.f;
    for (int k = 0; k < Dd; ++k) s = fmaf(yslT[k][r], u[k*Hh + h2], s);
    float* vw = ws + (which ? OFF_VW2 : OFF_VW1);
    vw[((size_t)(b*Hh + h2)*Tt + t)*Nn + r] = s;
  }
}

// ---------------- kernel 3: per-pair temporal online softmax, t-chunked LDS ----------------
__global__ __launch_bounds__(256) void k_attn(float* __restrict__ ws) {
  __shared__ __align__(16) float k_l[16][TT][HD];   // 8 KB
  __shared__ float q_l[TT][HD][Nn+1];               // 33.3 KB
  __shared__ float vw1_l[TT][16], vw2_l[TT][16];    // 1 KB
  const int tid = threadIdx.x;
  const int blk = blockIdx.x;         // (b*H+h)*4 + quarter
  const int quarter = blk & 3;
  const int bh = blk >> 2;
  const int b = bh >> 3;
  const int h = bh & 7;
  const int ch = h * HD;
  const int i0 = quarter * 16;
  const float* kk = ws + OFF_KK + (size_t)b*Tt*Nn*Dd;
  const float* qq = ws + OFF_QQ + (size_t)b*Tt*Nn*Dd;
  const float* vw1 = ws + OFF_VW1 + (size_t)bh*Tt*Nn;
  const float* vw2 = ws + OFF_VW2 + (size_t)bh*Tt*Nn;
  float* e = ws + OFF_E + (size_t)b*Nn*Nn;
  const int j = tid & 63, wq = tid >> 6;
  float m[4], Ssum[4], A1[4], A2[4];
  #pragma unroll
  for (int p = 0; p < 4; ++p) { m[p] = -1e30f; Ssum[p] = 0.f; A1[p] = 0.f; A2[p] = 0.f; }
  const float scale = 0.08838834764831845f; // 1/sqrt(128)

  for (int tc = 0; tc < Tt/TT; ++tc) {
    const int tbase = tc * TT;
    __syncthreads();   // protect LDS from previous chunk's readers
    // stage K: 16i*TT*16d = 512 float4; 2 per thread
    #pragma unroll
    for (int s = 0; s < 2; ++s) {
      int fi = tid + s*256;
      int d4 = fi & 3, ttl = (fi >> 2) & 7, il = fi >> 5;
      float4 v = *(const float4*)&kk[((size_t)(tbase + ttl)*Nn + i0 + il)*Dd + ch + d4*4];
      *(float4*)&k_l[il][ttl][d4*4] = v;
    }
    // stage Q transposed: TT*64*16 = 2048 float4; 8 per thread
    #pragma unroll
    for (int s = 0; s < 8; ++s) {
      int fi = tid + s*256;
      int d4 = fi & 3, jg = (fi >> 2) & 63, ttl = fi >> 8;
      float4 v = *(const float4*)&qq[((size_t)(tbase + ttl)*Nn + jg)*Dd + ch + d4*4];
      q_l[ttl][d4*4+0][jg] = v.x;
      q_l[ttl][d4*4+1][jg] = v.y;
      q_l[ttl][d4*4+2][jg] = v.z;
      q_l[ttl][d4*4+3][jg] = v.w;
    }
    // stage vw: 2*TT*16 = 256
    {
      int which = tid >> 7, ttl = (tid >> 4) & 7, ii = tid & 15;
      const float* src = which ? vw2 : vw1;
      float v = src[(size_t)(tbase + ttl)*Nn + i0 + ii];
      if (which) vw2_l[ttl][ii] = v; else vw1_l[ttl][ii] = v;
    }
    __syncthreads();

    for (int ttl = 0; ttl < TT; ++ttl) {
      float qr[16];
      #pragma unroll
      for (int d = 0; d < 16; ++d) qr[d] = q_l[ttl][d][j];
      #pragma unroll
      for (int p = 0; p < 4; ++p) {
        const int il = wq + 4*p;
        float4 k0 = *(const float4*)&k_l[il][ttl][0];
        float4 k1 = *(const float4*)&k_l[il][ttl][4];
        float4 k2 = *(const float4*)&k_l[il][ttl][8];
        float4 k3 = *(const float4*)&k_l[il][ttl][12];
        float s = 0.f;
        s = fmaf(qr[0],  k0.x, s); s = fmaf(qr[1],  k0.y, s);
        s = fmaf(qr[2],  k0.z, s); s = fmaf(qr[3],  k0.w, s);
        s = fmaf(qr[4],  k1.x, s); s = fmaf(qr[5],  k1.y, s);
        s = fmaf(qr[6],  k1.z, s); s = fmaf(qr[7],  k1.w, s);
        s = fmaf(qr[8],  k2.x, s); s = fmaf(qr[9],  k2.y, s);
        s = fmaf(qr[10], k2.z, s); s = fmaf(qr[11], k2.w, s);
        s = fmaf(qr[12], k3.x, s); s = fmaf(qr[13], k3.y, s);
        s = fmaf(qr[14], k3.z, s); s = fmaf(qr[15], k3.w, s);
        s *= scale;
        float mn = fmaxf(m[p], s);
        float cc2 = __expf(m[p] - mn);
        float pp = __expf(s - mn);
        Ssum[p] = fmaf(Ssum[p], cc2, pp);
        A1[p] = fmaf(A1[p], cc2, pp * vw1_l[ttl][il]);
        A2[p] = fmaf(A2[p], cc2, pp * vw2_l[ttl][il]);
        m[p] = mn;
      }
    }
  }
  #pragma unroll
  for (int p = 0; p < 4; ++p) {
    const int i = i0 + wq + 4*p;
    float inv = 1.f / Ssum[p];
    atomicAdd(&e[i*Nn + j], A1[p] * inv);
    atomicAdd(&e[j*Nn + i], A2[p] * inv);
  }
}

// ---------------- kernel 4: decode GRU step + vv ----------------
__global__ __launch_bounds__(384) void k_decode(
    const float* __restrict__ x, const float* __restrict__ W_hh,
    const float* __restrict__ b_hh, const float* __restrict__ W_val,
    const float* __restrict__ b_val, float* __restrict__ ws) {
  __shared__ float h_lds[4][Dd];
  __shared__ float g_lds[4][4*Dd];
  __shared__ float xt[4][Ss];
  const int tid = threadIdx.x;
  const int blk = blockIdx.x;
  const int row0 = blk * 4;
  const int b = row0 >> 6;
  const int n0 = row0 & 63;
  const float* ys = ws + OFF_YS;
  const float* Wx = ws + OFF_WX;
  const float* bxp = ws + OFF_BX;
  if (tid < Dd) {
    for (int r = 0; r < 4; ++r)
      h_lds[r][tid] = ys[(size_t)((Tt-1)*BN + row0 + r)*Dd + tid];
  }
  if (tid >= 320 && tid < 336) {
    int q = tid - 320; int r = q >> 2, s = q & 3;
    xt[r][s] = x[((size_t)(b*(Tt+1) + Tt)*Nn + (n0 + r))*Ss + s];
  }
  const int c = tid;
  const float bhh = b_hh[c];
  const float wx0 = Wx[0*G3 + c], wx1 = Wx[1*G3 + c], wx2 = Wx[2*G3 + c], wx3 = Wx[3*G3 + c];
  const float bxv = bxp[c];
  __syncthreads();
  float acc[4] = {bhh, bhh, bhh, bhh};
  for (int k = 0; k < Dd; k += 4) {
    float w0 = W_hh[(k+0)*G3 + c];
    float w1 = W_hh[(k+1)*G3 + c];
    float w2 = W_hh[(k+2)*G3 + c];
    float w3 = W_hh[(k+3)*G3 + c];
    #pragma unroll
    for (int r = 0; r < 4; ++r) {
      float4 hv = *(const float4*)&h_lds[r][k];
      acc[r] = fmaf(hv.x, w0, acc[r]);
      acc[r] = fmaf(hv.y, w1, acc[r]);
      acc[r] = fmaf(hv.z, w2, acc[r]);
      acc[r] = fmaf(hv.w, w3, acc[r]);
    }
  }
  float gi[4];
  #pragma unroll
  for (int r = 0; r < 4; ++r) {
    float g = bxv;
    g = fmaf(xt[r][0], wx0, g);
    g = fmaf(xt[r][1], wx1, g);
    g = fmaf(xt[r][2], wx2, g);
    g = fmaf(xt[r][3], wx3, g);
    gi[r] = g;
  }
  if (c < 2*Dd) {
    #pragma unroll
    for (int r = 0; r < 4; ++r) g_lds[r][c] = acc[r] + gi[r];
  } else {
    #pragma unroll
    for (int r = 0; r < 4; ++r) { g_lds[r][c] = gi[r]; g_lds[r][c + Dd] = acc[r]; }
  }
  __syncthreads();
  if (tid < Dd) {
    const int d = tid;
    #pragma unroll
    for (int r = 0; r < 4; ++r) {
      float rg = fast_sigmoid(g_lds[r][d]);
      float zg = fast_sigmoid(g_lds[r][Dd + d]);
      float ng = fast_tanh(fmaf(rg, g_lds[r][3*Dd + d], g_lds[r][2*Dd + d]));
      float hn = fmaf(zg, h_lds[r][d] - ng, ng);
      h_lds[r][d] = hn;
    }
  }
  __syncthreads();
  if (tid < Dd) {
    const int c2 = tid;
    for (int r = 0; r < 4; ++r) {
      float a = b_val[c2];
      for (int k = 0; k < Dd; k += 4) {
        float4 hv = *(const float4*)&h_lds[r][k];
        a = fmaf(hv.x, W_val[(k+0)*Dd + c2], a);
        a = fmaf(hv.y, W_val[(k+1)*Dd + c2], a);
        a = fmaf(hv.z, W_val[(k+2)*Dd + c2], a);
        a = fmaf(hv.w, W_val[(k+3)*Dd + c2], a);
      }
      ws[OFF_VV + (size_t)(row0 + r)*Dd + c2] = a;
    }
  }
}

// ---------------- kernel 5: weight/p/dec/mu/sig ----------------
__global__ __launch_bounds__(256) void k_final(
    const float* __restrict__ W_dec, const float* __restrict__ b_dec,
    const float* __restrict__ W_mu, const float* __restrict__ b_mu,
    const float* __restrict__ W_sig, const float* __restrict__ b_sig,
    const float* __restrict__ b_att, float* __restrict__ ws,
    float* __restrict__ out) {
  __shared__ float vvl[64][Dd];  // 32KB
  __shared__ float wl[16][64];
  __shared__ float pl[16][Dd];
  __shared__ float ddl[16][Dd];
  const int tid = threadIdx.x;
  const int blk = blockIdx.x;
  const int b = blk >> 2, iq = blk & 3, i0 = iq*16;
  const float* vv = ws + OFF_VV + (size_t)b*64*Dd;
  const float* e = ws + OFF_E + (size_t)b*Nn*Nn;
  const float batt = b_att[0];
  for (int idx = tid; idx < 64*Dd; idx += 256) ((float*)vvl)[idx] = vv[idx];
  for (int idx = tid; idx < 16*64; idx += 256) {
    int il = idx >> 6, jj = idx & 63;
    int i = i0 + il;
    wl[il][jj] = (i == jj) ? 0.f : fast_tanh(e[i*Nn + jj] + batt + 0.5f);
  }
  __syncthreads();
  {
    const int d = tid & 127, ih = tid >> 7;
    #pragma unroll
    for (int kk2 = 0; kk2 < 8; ++kk2) {
      int il = ih*8 + kk2;
      float a = 0.f;
      for (int jj = 0; jj < 64; ++jj) a = fmaf(wl[il][jj], vvl[jj][d], a);
      pl[il][d] = a * (1.f/64.f);
    }
  }
  __syncthreads();
  {
    const int e2 = tid & 127, ih = tid >> 7;
    #pragma unroll
    for (int kk2 = 0; kk2 < 8; ++kk2) {
      int il = ih*8 + kk2;
      float a = b_dec[e2];
      for (int c2 = 0; c2 < Dd; ++c2) a = fmaf(vvl[i0 + il][c2], W_dec[c2*Dd + e2], a);
      for (int c2 = 0; c2 < Dd; ++c2) a = fmaf(pl[il][c2], W_dec[(Dd + c2)*Dd + e2], a);
      ddl[il][e2] = a;
    }
  }
  __syncthreads();
  if (tid < 128) {
    const int il = tid >> 3, g = tid & 7, which = g >> 2, s = g & 3;
    const float* W = which ? W_sig : W_mu;
    float a = which ? b_sig[s] : b_mu[s];
    for (int k = 0; k < Dd; ++k) a = fmaf(ddl[il][k], W[k*Ss + s], a);
    if (which) a = 1.f/(1.f + __expf(-a)) + 1e-6f;
    out[(size_t)which*(Bb*Nn*Ss) + (size_t)(b*64 + i0 + il)*Ss + s] = a;
  }
}

extern "C" void kernel_launch(void* const* d_in, const int* in_sizes, int n_in,
                              void* d_out, int out_size, void* d_ws, size_t ws_size,
                              hipStream_t stream) {
  const float* x     = (const float*)d_in[0];
  const float* W_se  = (const float*)d_in[1];
  const float* b_se  = (const float*)d_in[2];
  const float* W_init= (const float*)d_in[3];
  const float* b_init= (const float*)d_in[4];
  const float* W_ih  = (const float*)d_in[5];
  const float* W_hh  = (const float*)d_in[6];
  const float* b_ih  = (const float*)d_in[7];
  const float* b_hh  = (const float*)d_in[8];
  const float* W_kc  = (const float*)d_in[9];
  const float* W_qc  = (const float*)d_in[10];
  const float* W_vc  = (const float*)d_in[11];
  const float* W_att = (const float*)d_in[12];
  const float* b_att = (const float*)d_in[13];
  const float* W_val = (const float*)d_in[14];
  const float* b_val = (const float*)d_in[15];
  const float* W_dec = (const float*)d_in[16];
  const float* b_dec = (const float*)d_in[17];
  const float* W_mu  = (const float*)d_in[18];
  const float* b_mu  = (const float*)d_in[19];
  const float* W_sig = (const float*)d_in[20];
  const float* b_sig = (const float*)d_in[21];
  float* ws = (float*)d_ws;
  float* out = (float*)d_out;

  if (ws_size < (size_t)WS_FLOATS * sizeof(float)) return;

  hipMemsetAsync(ws + OFF_E, 0, (size_t)Bb*Nn*Nn*sizeof(float), stream);
  k_precompute<<<65, 384, 0, stream>>>(W_se, b_se, W_ih, b_ih, W_hh, W_vc, W_att, ws);
  k_gru<<<BN/4, 384, 64*G3*sizeof(uint32_t), stream>>>(x, W_init, b_init, b_hh, ws);
  k_kqv<<<Bb*Tt, 256, 0, stream>>>(W_kc, W_qc, ws);
  k_attn<<<Bb*Hh*4, 256, 0, stream>>>(ws);
  k_decode<<<BN/4, 384, 0, stream>>>(x, W_hh, b_hh, W_val, b_val, ws);
  k_final<<<Bb*4, 256, 0, stream>>>(W_dec, b_dec, W_mu, b_mu, W_sig, b_sig, b_att, ws, out);
}

// Round 7
// 383.491 us; speedup vs baseline: 1.9867x; 1.0709x over previous
//
#include <hip/hip_runtime.h>
#include <math.h>

#define Bb 16
#define Tt 64
#define Nn 64
#define Ss 4
#define Dd 128
#define Hh 8
#define HD 16
#define BN 1024
#define G3 384   // 3*D
#define TT 8     // t-chunk for k_attn

// workspace layout (in floats)
#define OFF_WX   0                              // 4*384
#define OFF_BX   1536                           // 384
#define OFF_U1   1920                           // 128*8
#define OFF_U2   2944                           // 128*8
#define OFF_YS   4096                           // T*BN*D
#define OFF_KK   (OFF_YS + Tt*BN*Dd)            // [(b*T+t)*N + n]*D  (c = h*16+d)
#define OFF_QQ   (OFF_KK + Bb*Tt*Nn*Dd)
#define OFF_VW1  (OFF_QQ + Bb*Tt*Nn*Dd)         // [b][h][t][n]
#define OFF_VW2  (OFF_VW1 + Bb*Hh*Tt*Nn)
#define OFF_E    (OFF_VW2 + Bb*Hh*Tt*Nn)        // B*N*N
#define OFF_VV   (OFF_E + Bb*Nn*Nn)             // BN*D
#define WS_FLOATS (OFF_VV + BN*Dd)
// transient: f16x2-packed W_hh [64 pairs][384 cols] lives in KK region pre-k_kqv
#define OFF_WT   OFF_KK                         // 24576 u32 = 96 KB

typedef _Float16 half2_t __attribute__((ext_vector_type(2)));

__device__ __forceinline__ float fast_sigmoid(float v) {
  return 1.f / (1.f + __expf(-v));
}
__device__ __forceinline__ float fast_tanh(float v) {
  float e2 = __expf(2.f * v);
  return 1.f - 2.f / (e2 + 1.f);
}
__device__ __forceinline__ float fdot2(uint32_t a, uint32_t b, float c) {
  half2_t av = __builtin_bit_cast(half2_t, a);
  half2_t bv = __builtin_bit_cast(half2_t, b);
#if __has_builtin(__builtin_amdgcn_fdot2)
  return __builtin_amdgcn_fdot2(av, bv, c, false);
#else
  return c + (float)av.x * (float)bv.x + (float)av.y * (float)bv.y;
#endif
}

// ---------------- kernel 0: fold weights + pack W_hh to f16x2 ----------------
__global__ __launch_bounds__(384) void k_precompute(
    const float* __restrict__ W_se, const float* __restrict__ b_se,
    const float* __restrict__ W_ih, const float* __restrict__ b_ih,
    const float* __restrict__ W_hh,
    const float* __restrict__ W_vc, const float* __restrict__ W_att,
    float* __restrict__ ws) {
  const int tid = threadIdx.x;
  if (blockIdx.x > 0) {
    const int p = blockIdx.x - 1;     // pair index 0..63
    uint32_t* WT = (uint32_t*)(ws + OFF_WT);
    if (tid < G3) {
      float w0 = W_hh[(size_t)(2*p)*G3 + tid];
      float w1 = W_hh[(size_t)(2*p+1)*G3 + tid];
      half2_t hv; hv.x = (_Float16)w0; hv.y = (_Float16)w1;
      WT[(size_t)p*G3 + tid] = __builtin_bit_cast(uint32_t, hv);
    }
    return;
  }
  const int c = tid; // 0..383
  float* Wx = ws + OFF_WX; float* bx = ws + OFF_BX;
  float* u1 = ws + OFF_U1; float* u2 = ws + OFF_U2;
  float accb = b_ih[c];
  float a0 = 0.f, a1 = 0.f, a2 = 0.f, a3 = 0.f;
  for (int k = 0; k < Dd; ++k) {
    float w = W_ih[k*G3 + c];
    accb = fmaf(b_se[k], w, accb);
    a0 = fmaf(W_se[0*Dd + k], w, a0);
    a1 = fmaf(W_se[1*Dd + k], w, a1);
    a2 = fmaf(W_se[2*Dd + k], w, a2);
    a3 = fmaf(W_se[3*Dd + k], w, a3);
  }
  bx[c] = accb;
  Wx[0*G3 + c] = a0; Wx[1*G3 + c] = a1; Wx[2*G3 + c] = a2; Wx[3*G3 + c] = a3;
  for (int idx = c; idx < Dd*Hh; idx += 384) {
    int k = idx >> 3, h = idx & 7;
    float s1 = 0.f, s2 = 0.f;
    for (int d = 0; d < HD; ++d) {
      float v = W_vc[k*Dd + h*HD + d];
      s1 = fmaf(v, W_att[h*HD + d], s1);
      s2 = fmaf(v, W_att[Dd + h*HD + d], s2);
    }
    u1[k*Hh + h] = s1;
    u2[k*Hh + h] = s2;
  }
}

// ---------------- kernel 1: GRU, W_hh f16x2 LDS-resident, k-split 768 threads ----------------
// 4 rows/block, 256 blocks, 12 waves/CU. Thread = (col c, k-half kh); kh0 does
// h-pairs 0..31, kh1 pairs 32..63. Partials summed in the activation phase.
__global__ __launch_bounds__(768) void k_gru(
    const float* __restrict__ x, const float* __restrict__ W_init,
    const float* __restrict__ b_init,
    const float* __restrict__ b_hh, float* __restrict__ ws) {
  extern __shared__ uint32_t WTl[];               // 24576 u32 = 96 KB
  __shared__ __align__(16) uint32_t hp[4][Dd/2];  // f16x2 h, 1 KB
  __shared__ float ga[4][G3];                     // kh0 partial (+biases), 6 KB
  __shared__ float gb[4][G3];                     // kh1 partial, 6 KB
  __shared__ float gix[4][Dd];                    // gi for n-gate, 2 KB
  __shared__ float xt_l[Tt+1][4][Ss];             // 4.1 KB
  const int tid = threadIdx.x;
  const int kh = (tid >= G3) ? 1 : 0;             // wave-aligned (384 = 6 waves)
  const int c = tid - kh*G3;
  const int blk = blockIdx.x;
  const int row0 = blk * 4;
  const int b = row0 >> 6;
  const int n0 = row0 & 63;
  float* ys = ws + OFF_YS;
  const float* Wx = ws + OFF_WX;
  const float* bxp = ws + OFF_BX;
  const uint32_t* WTg = (const uint32_t*)(ws + OFF_WT);

  for (int i4 = tid; i4 < (64*G3)/4; i4 += 768)
    *(uint4*)&WTl[i4*4] = *(const uint4*)&WTg[i4*4];

  for (int idx = tid; idx < (Tt+1)*4*Ss; idx += 768) {
    int t = idx >> 4, r = (idx >> 2) & 3, s = idx & 3;
    xt_l[t][r][s] = x[((size_t)(b*(Tt+1) + t)*Nn + (n0 + r))*Ss + s];
  }
  __syncthreads();

  // activation thread: tid<512 owns (row r, dim d); h kept f32 in register
  float hprev = 0.f;
  int r = 0, d = 0;
  if (tid < 4*Dd) {
    r = tid >> 7; d = tid & 127;
    float h0 = b_init[d];
    #pragma unroll
    for (int s = 0; s < Ss; ++s)
      h0 = fmaf(xt_l[0][r][s], W_init[s*Dd + d], h0);
    hprev = h0;
    ((_Float16*)hp)[r*Dd + d] = (_Float16)h0;
  }
  const float bhh = b_hh[c];
  const float wx0 = Wx[0*G3 + c], wx1 = Wx[1*G3 + c], wx2 = Wx[2*G3 + c], wx3 = Wx[3*G3 + c];
  const float bxv = bxp[c];
  const int pbase = kh * 32;
  __syncthreads();

  for (int t = 0; t < Tt; ++t) {
    // partial gh: 32 pairs per thread
    float acc0 = 0.f, acc1 = 0.f, acc2 = 0.f, acc3 = 0.f;
    #pragma unroll
    for (int p4 = 0; p4 < 8; ++p4) {
      const int pp = pbase + p4*4;
      uint4 h0 = *(const uint4*)&hp[0][pp];
      uint4 h1 = *(const uint4*)&hp[1][pp];
      uint4 h2 = *(const uint4*)&hp[2][pp];
      uint4 h3 = *(const uint4*)&hp[3][pp];
      uint32_t w0 = WTl[(pp+0)*G3 + c];
      uint32_t w1 = WTl[(pp+1)*G3 + c];
      uint32_t w2 = WTl[(pp+2)*G3 + c];
      uint32_t w3 = WTl[(pp+3)*G3 + c];
      acc0 = fdot2(h0.x, w0, acc0); acc0 = fdot2(h0.y, w1, acc0);
      acc0 = fdot2(h0.z, w2, acc0); acc0 = fdot2(h0.w, w3, acc0);
      acc1 = fdot2(h1.x, w0, acc1); acc1 = fdot2(h1.y, w1, acc1);
      acc1 = fdot2(h1.z, w2, acc1); acc1 = fdot2(h1.w, w3, acc1);
      acc2 = fdot2(h2.x, w0, acc2); acc2 = fdot2(h2.y, w1, acc2);
      acc2 = fdot2(h2.z, w2, acc2); acc2 = fdot2(h2.w, w3, acc2);
      acc3 = fdot2(h3.x, w0, acc3); acc3 = fdot2(h3.y, w1, acc3);
      acc3 = fdot2(h3.z, w2, acc3); acc3 = fdot2(h3.w, w3, acc3);
    }
    float accs[4] = {acc0, acc1, acc2, acc3};
    if (kh == 0) {
      float gi[4];
      #pragma unroll
      for (int rr = 0; rr < 4; ++rr) {
        float g = bxv;
        g = fmaf(xt_l[t][rr][0], wx0, g);
        g = fmaf(xt_l[t][rr][1], wx1, g);
        g = fmaf(xt_l[t][rr][2], wx2, g);
        g = fmaf(xt_l[t][rr][3], wx3, g);
        gi[rr] = g;
      }
      if (c < 2*Dd) {
        #pragma unroll
        for (int rr = 0; rr < 4; ++rr) ga[rr][c] = accs[rr] + gi[rr] + bhh;
      } else {
        #pragma unroll
        for (int rr = 0; rr < 4; ++rr) {
          ga[rr][c] = accs[rr] + bhh;     // hn partial (hidden bias)
          gix[rr][c - 2*Dd] = gi[rr];     // inn (input part incl. bx)
        }
      }
    } else {
      #pragma unroll
      for (int rr = 0; rr < 4; ++rr) gb[rr][c] = accs[rr];
    }
    __syncthreads();
    if (tid < 4*Dd) {
      float rg = fast_sigmoid(ga[r][d] + gb[r][d]);
      float zg = fast_sigmoid(ga[r][Dd + d] + gb[r][Dd + d]);
      float hn_h = ga[r][2*Dd + d] + gb[r][2*Dd + d];
      float ng = fast_tanh(fmaf(rg, hn_h, gix[r][d]));
      float hnew = fmaf(zg, hprev - ng, ng);   // (1-z)*n + z*h
      hprev = hnew;
      ((_Float16*)hp)[r*Dd + d] = (_Float16)hnew;
      ys[(size_t)(t*BN + row0 + r)*Dd + d] = hnew;
    }
    __syncthreads();
  }
}

// ---------------- kernel 2: k,q projections, 8x8 register-tile GEMM ----------------
__global__ __launch_bounds__(256) void k_kqv(
    const float* __restrict__ W_kc, const float* __restrict__ W_qc,
    float* __restrict__ ws) {
  __shared__ __align__(16) float yslT[Dd][68];  // transposed, padded: 34.8 KB
  const int tid = threadIdx.x;
  const int blk = blockIdx.x;    // b*T + t
  const int b = blk >> 6;
  const int t = blk & 63;
  const float* ysrc = ws + OFF_YS + ((size_t)t*BN + b*64)*Dd;
  for (int idx = tid; idx < 64*Dd/4; idx += 256) {
    int r = idx >> 5, k4 = idx & 31;
    float4 v = *(const float4*)&ysrc[r*Dd + k4*4];
    yslT[k4*4+0][r] = v.x;
    yslT[k4*4+1][r] = v.y;
    yslT[k4*4+2][r] = v.z;
    yslT[k4*4+3][r] = v.w;
  }
  __syncthreads();

  const int rg = tid >> 5;          // 0..7  (row group)
  const int cg = tid & 31;          // 0..31 (col group)
  const int row0 = rg * 8;
  const float* Wm = (cg < 16) ? W_kc : W_qc;
  const int col0 = (cg & 15) * 8;
  const float* wp = Wm + col0;

  float acc[8][8];
  #pragma unroll
  for (int r = 0; r < 8; ++r)
    #pragma unroll
    for (int cc = 0; cc < 8; ++cc) acc[r][cc] = 0.f;

  float4 bv0 = *(const float4*)&wp[0];
  float4 bv1 = *(const float4*)&wp[4];
  for (int k = 0; k < Dd; ++k) {
    const int kn = (k + 1) & 127;
    float4 nb0 = *(const float4*)&wp[kn*Dd];
    float4 nb1 = *(const float4*)&wp[kn*Dd + 4];
    float4 a0 = *(const float4*)&yslT[k][row0];
    float4 a1 = *(const float4*)&yslT[k][row0 + 4];
    float ar[8] = {a0.x, a0.y, a0.z, a0.w, a1.x, a1.y, a1.z, a1.w};
    float br[8] = {bv0.x, bv0.y, bv0.z, bv0.w, bv1.x, bv1.y, bv1.z, bv1.w};
    #pragma unroll
    for (int r = 0; r < 8; ++r)
      #pragma unroll
      for (int cc = 0; cc < 8; ++cc)
        acc[r][cc] = fmaf(ar[r], br[cc], acc[r][cc]);
    bv0 = nb0; bv1 = nb1;
  }

  float* dst = ws + ((cg < 16) ? OFF_KK : OFF_QQ);
  const size_t base = (size_t)blk * Nn * Dd;
  #pragma unroll
  for (int r = 0; r < 8; ++r) {
    float4 o0 = {acc[r][0], acc[r][1], acc[r][2], acc[r][3]};
    float4 o1 = {acc[r][4], acc[r][5], acc[r][6], acc[r][7]};
    *(float4*)&dst[base + (size_t)(row0 + r)*Dd + col0] = o0;
    *(float4*)&dst[base + (size_t)(row0 + r)*Dd + col0 + 4] = o1;
  }

  const float* u1 = ws + OFF_U1;
  const float* u2 = ws + OFF_U2;
  for (int idx = tid; idx < 64*HD; idx += 256) {
    int r = idx >> 4, g = idx & 15, h2 = g >> 1, which = g & 1;
    const float* u = which ? u2 : u1;
    float s = 0.f;
    for (int k = 0; k < Dd; ++k) s = fmaf(yslT[k][r], u[k*Hh + h2], s);
    float* vw = ws + (which ? OFF_VW2 : OFF_VW1);
    vw[((size_t)(b*Hh + h2)*Tt + t)*Nn + r] = s;
  }
}

// ---------------- kernel 3: per-pair temporal online softmax, t-chunked LDS ----------------
__global__ __launch_bounds__(256) void k_attn(float* __restrict__ ws) {
  __shared__ __align__(16) float k_l[16][TT][HD];   // 8 KB
  __shared__ float q_l[TT][HD][Nn+1];               // 33.3 KB
  __shared__ float vw1_l[TT][16], vw2_l[TT][16];    // 1 KB
  const int tid = threadIdx.x;
  const int blk = blockIdx.x;         // (b*H+h)*4 + quarter
  const int quarter = blk & 3;
  const int bh = blk >> 2;
  const int b = bh >> 3;
  const int h = bh & 7;
  const int ch = h * HD;
  const int i0 = quarter * 16;
  const float* kk = ws + OFF_KK + (size_t)b*Tt*Nn*Dd;
  const float* qq = ws + OFF_QQ + (size_t)b*Tt*Nn*Dd;
  const float* vw1 = ws + OFF_VW1 + (size_t)bh*Tt*Nn;
  const float* vw2 = ws + OFF_VW2 + (size_t)bh*Tt*Nn;
  float* e = ws + OFF_E + (size_t)b*Nn*Nn;
  const int j = tid & 63, wq = tid >> 6;
  float m[4], Ssum[4], A1[4], A2[4];
  #pragma unroll
  for (int p = 0; p < 4; ++p) { m[p] = -1e30f; Ssum[p] = 0.f; A1[p] = 0.f; A2[p] = 0.f; }
  const float scale = 0.08838834764831845f; // 1/sqrt(128)

  for (int tc = 0; tc < Tt/TT; ++tc) {
    const int tbase = tc * TT;
    __syncthreads();
    #pragma unroll
    for (int s = 0; s < 2; ++s) {
      int fi = tid + s*256;
      int d4 = fi & 3, ttl = (fi >> 2) & 7, il = fi >> 5;
      float4 v = *(const float4*)&kk[((size_t)(tbase + ttl)*Nn + i0 + il)*Dd + ch + d4*4];
      *(float4*)&k_l[il][ttl][d4*4] = v;
    }
    #pragma unroll
    for (int s = 0; s < 8; ++s) {
      int fi = tid + s*256;
      int d4 = fi & 3, jg = (fi >> 2) & 63, ttl = fi >> 8;
      float4 v = *(const float4*)&qq[((size_t)(tbase + ttl)*Nn + jg)*Dd + ch + d4*4];
      q_l[ttl][d4*4+0][jg] = v.x;
      q_l[ttl][d4*4+1][jg] = v.y;
      q_l[ttl][d4*4+2][jg] = v.z;
      q_l[ttl][d4*4+3][jg] = v.w;
    }
    {
      int which = tid >> 7, ttl = (tid >> 4) & 7, ii = tid & 15;
      const float* src = which ? vw2 : vw1;
      float v = src[(size_t)(tbase + ttl)*Nn + i0 + ii];
      if (which) vw2_l[ttl][ii] = v; else vw1_l[ttl][ii] = v;
    }
    __syncthreads();

    for (int ttl = 0; ttl < TT; ++ttl) {
      float qr[16];
      #pragma unroll
      for (int dd = 0; dd < 16; ++dd) qr[dd] = q_l[ttl][dd][j];
      #pragma unroll
      for (int p = 0; p < 4; ++p) {
        const int il = wq + 4*p;
        float4 k0 = *(const float4*)&k_l[il][ttl][0];
        float4 k1 = *(const float4*)&k_l[il][ttl][4];
        float4 k2 = *(const float4*)&k_l[il][ttl][8];
        float4 k3 = *(const float4*)&k_l[il][ttl][12];
        float s = 0.f;
        s = fmaf(qr[0],  k0.x, s); s = fmaf(qr[1],  k0.y, s);
        s = fmaf(qr[2],  k0.z, s); s = fmaf(qr[3],  k0.w, s);
        s = fmaf(qr[4],  k1.x, s); s = fmaf(qr[5],  k1.y, s);
        s = fmaf(qr[6],  k1.z, s); s = fmaf(qr[7],  k1.w, s);
        s = fmaf(qr[8],  k2.x, s); s = fmaf(qr[9],  k2.y, s);
        s = fmaf(qr[10], k2.z, s); s = fmaf(qr[11], k2.w, s);
        s = fmaf(qr[12], k3.x, s); s = fmaf(qr[13], k3.y, s);
        s = fmaf(qr[14], k3.z, s); s = fmaf(qr[15], k3.w, s);
        s *= scale;
        float mn = fmaxf(m[p], s);
        float cc2 = __expf(m[p] - mn);
        float pp = __expf(s - mn);
        Ssum[p] = fmaf(Ssum[p], cc2, pp);
        A1[p] = fmaf(A1[p], cc2, pp * vw1_l[ttl][il]);
        A2[p] = fmaf(A2[p], cc2, pp * vw2_l[ttl][il]);
        m[p] = mn;
      }
    }
  }
  #pragma unroll
  for (int p = 0; p < 4; ++p) {
    const int i = i0 + wq + 4*p;
    float inv = 1.f / Ssum[p];
    atomicAdd(&e[i*Nn + j], A1[p] * inv);
    atomicAdd(&e[j*Nn + i], A2[p] * inv);
  }
}

// ---------------- kernel 4: decode GRU step + vv ----------------
__global__ __launch_bounds__(384) void k_decode(
    const float* __restrict__ x, const float* __restrict__ W_hh,
    const float* __restrict__ b_hh, const float* __restrict__ W_val,
    const float* __restrict__ b_val, float* __restrict__ ws) {
  __shared__ float h_lds[4][Dd];
  __shared__ float g_lds[4][4*Dd];
  __shared__ float xt[4][Ss];
  const int tid = threadIdx.x;
  const int blk = blockIdx.x;
  const int row0 = blk * 4;
  const int b = row0 >> 6;
  const int n0 = row0 & 63;
  const float* ys = ws + OFF_YS;
  const float* Wx = ws + OFF_WX;
  const float* bxp = ws + OFF_BX;
  if (tid < Dd) {
    for (int r = 0; r < 4; ++r)
      h_lds[r][tid] = ys[(size_t)((Tt-1)*BN + row0 + r)*Dd + tid];
  }
  if (tid >= 320 && tid < 336) {
    int q = tid - 320; int r = q >> 2, s = q & 3;
    xt[r][s] = x[((size_t)(b*(Tt+1) + Tt)*Nn + (n0 + r))*Ss + s];
  }
  const int c = tid;
  const float bhh = b_hh[c];
  const float wx0 = Wx[0*G3 + c], wx1 = Wx[1*G3 + c], wx2 = Wx[2*G3 + c], wx3 = Wx[3*G3 + c];
  const float bxv = bxp[c];
  __syncthreads();
  float acc[4] = {bhh, bhh, bhh, bhh};
  for (int k = 0; k < Dd; k += 4) {
    float w0 = W_hh[(k+0)*G3 + c];
    float w1 = W_hh[(k+1)*G3 + c];
    float w2 = W_hh[(k+2)*G3 + c];
    float w3 = W_hh[(k+3)*G3 + c];
    #pragma unroll
    for (int r = 0; r < 4; ++r) {
      float4 hv = *(const float4*)&h_lds[r][k];
      acc[r] = fmaf(hv.x, w0, acc[r]);
      acc[r] = fmaf(hv.y, w1, acc[r]);
      acc[r] = fmaf(hv.z, w2, acc[r]);
      acc[r] = fmaf(hv.w, w3, acc[r]);
    }
  }
  float gi[4];
  #pragma unroll
  for (int r = 0; r < 4; ++r) {
    float g = bxv;
    g = fmaf(xt[r][0], wx0, g);
    g = fmaf(xt[r][1], wx1, g);
    g = fmaf(xt[r][2], wx2, g);
    g = fmaf(xt[r][3], wx3, g);
    gi[r] = g;
  }
  if (c < 2*Dd) {
    #pragma unroll
    for (int r = 0; r < 4; ++r) g_lds[r][c] = acc[r] + gi[r];
  } else {
    #pragma unroll
    for (int r = 0; r < 4; ++r) { g_lds[r][c] = gi[r]; g_lds[r][c + Dd] = acc[r]; }
  }
  __syncthreads();
  if (tid < Dd) {
    const int d = tid;
    #pragma unroll
    for (int r = 0; r < 4; ++r) {
      float rg = fast_sigmoid(g_lds[r][d]);
      float zg = fast_sigmoid(g_lds[r][Dd + d]);
      float ng = fast_tanh(fmaf(rg, g_lds[r][3*Dd + d], g_lds[r][2*Dd + d]));
      float hn = fmaf(zg, h_lds[r][d] - ng, ng);
      h_lds[r][d] = hn;
    }
  }
  __syncthreads();
  if (tid < Dd) {
    const int c2 = tid;
    for (int r = 0; r < 4; ++r) {
      float a = b_val[c2];
      for (int k = 0; k < Dd; k += 4) {
        float4 hv = *(const float4*)&h_lds[r][k];
        a = fmaf(hv.x, W_val[(k+0)*Dd + c2], a);
        a = fmaf(hv.y, W_val[(k+1)*Dd + c2], a);
        a = fmaf(hv.z, W_val[(k+2)*Dd + c2], a);
        a = fmaf(hv.w, W_val[(k+3)*Dd + c2], a);
      }
      ws[OFF_VV + (size_t)(row0 + r)*Dd + c2] = a;
    }
  }
}

// ---------------- kernel 5: weight/p/dec/mu/sig ----------------
__global__ __launch_bounds__(256) void k_final(
    const float* __restrict__ W_dec, const float* __restrict__ b_dec,
    const float* __restrict__ W_mu, const float* __restrict__ b_mu,
    const float* __restrict__ W_sig, const float* __restrict__ b_sig,
    const float* __restrict__ b_att, float* __restrict__ ws,
    float* __restrict__ out) {
  __shared__ float vvl[64][Dd];  // 32KB
  __shared__ float wl[16][64];
  __shared__ float pl[16][Dd];
  __shared__ float ddl[16][Dd];
  const int tid = threadIdx.x;
  const int blk = blockIdx.x;
  const int b = blk >> 2, iq = blk & 3, i0 = iq*16;
  const float* vv = ws + OFF_VV + (size_t)b*64*Dd;
  const float* e = ws + OFF_E + (size_t)b*Nn*Nn;
  const float batt = b_att[0];
  for (int idx = tid; idx < 64*Dd; idx += 256) ((float*)vvl)[idx] = vv[idx];
  for (int idx = tid; idx < 16*64; idx += 256) {
    int il = idx >> 6, jj = idx & 63;
    int i = i0 + il;
    wl[il][jj] = (i == jj) ? 0.f : fast_tanh(e[i*Nn + jj] + batt + 0.5f);
  }
  __syncthreads();
  {
    const int d = tid & 127, ih = tid >> 7;
    #pragma unroll
    for (int kk2 = 0; kk2 < 8; ++kk2) {
      int il = ih*8 + kk2;
      float a = 0.f;
      for (int jj = 0; jj < 64; ++jj) a = fmaf(wl[il][jj], vvl[jj][d], a);
      pl[il][d] = a * (1.f/64.f);
    }
  }
  __syncthreads();
  {
    const int e2 = tid & 127, ih = tid >> 7;
    #pragma unroll
    for (int kk2 = 0; kk2 < 8; ++kk2) {
      int il = ih*8 + kk2;
      float a = b_dec[e2];
      for (int c2 = 0; c2 < Dd; ++c2) a = fmaf(vvl[i0 + il][c2], W_dec[c2*Dd + e2], a);
      for (int c2 = 0; c2 < Dd; ++c2) a = fmaf(pl[il][c2], W_dec[(Dd + c2)*Dd + e2], a);
      ddl[il][e2] = a;
    }
  }
  __syncthreads();
  if (tid < 128) {
    const int il = tid >> 3, g = tid & 7, which = g >> 2, s = g & 3;
    const float* W = which ? W_sig : W_mu;
    float a = which ? b_sig[s] : b_mu[s];
    for (int k = 0; k < Dd; ++k) a = fmaf(ddl[il][k], W[k*Ss + s], a);
    if (which) a = 1.f/(1.f + __expf(-a)) + 1e-6f;
    out[(size_t)which*(Bb*Nn*Ss) + (size_t)(b*64 + i0 + il)*Ss + s] = a;
  }
}

extern "C" void kernel_launch(void* const* d_in, const int* in_sizes, int n_in,
                              void* d_out, int out_size, void* d_ws, size_t ws_size,
                              hipStream_t stream) {
  const float* x     = (const float*)d_in[0];
  const float* W_se  = (const float*)d_in[1];
  const float* b_se  = (const float*)d_in[2];
  const float* W_init= (const float*)d_in[3];
  const float* b_init= (const float*)d_in[4];
  const float* W_ih  = (const float*)d_in[5];
  const float* W_hh  = (const float*)d_in[6];
  const float* b_ih  = (const float*)d_in[7];
  const float* b_hh  = (const float*)d_in[8];
  const float* W_kc  = (const float*)d_in[9];
  const float* W_qc  = (const float*)d_in[10];
  const float* W_vc  = (const float*)d_in[11];
  const float* W_att = (const float*)d_in[12];
  const float* b_att = (const float*)d_in[13];
  const float* W_val = (const float*)d_in[14];
  const float* b_val = (const float*)d_in[15];
  const float* W_dec = (const float*)d_in[16];
  const float* b_dec = (const float*)d_in[17];
  const float* W_mu  = (const float*)d_in[18];
  const float* b_mu  = (const float*)d_in[19];
  const float* W_sig = (const float*)d_in[20];
  const float* b_sig = (const float*)d_in[21];
  float* ws = (float*)d_ws;
  float* out = (float*)d_out;

  if (ws_size < (size_t)WS_FLOATS * sizeof(float)) return;

  hipMemsetAsync(ws + OFF_E, 0, (size_t)Bb*Nn*Nn*sizeof(float), stream);
  k_precompute<<<65, 384, 0, stream>>>(W_se, b_se, W_ih, b_ih, W_hh, W_vc, W_att, ws);
  k_gru<<<BN/4, 768, 64*G3*sizeof(uint32_t), stream>>>(x, W_init, b_init, b_hh, ws);
  k_kqv<<<Bb*Tt, 256, 0, stream>>>(W_kc, W_qc, ws);
  k_attn<<<Bb*Hh*4, 256, 0, stream>>>(ws);
  k_decode<<<BN/4, 384, 0, stream>>>(x, W_hh, b_hh, W_val, b_val, ws);
  k_final<<<Bb*4, 256, 0, stream>>>(W_dec, b_dec, W_mu, b_mu, W_sig, b_sig, b_att, ws, out);
}